// Round 2
// baseline (1939.989 us; speedup 1.0000x reference)
//
#include <hip/hip_runtime.h>
#include <stdint.h>

typedef unsigned short u16;
typedef __attribute__((ext_vector_type(8))) short short8;
typedef __attribute__((ext_vector_type(4))) float f32x4;

// ---------------- numeric helpers ----------------
__device__ __forceinline__ float bf2f(u16 v) {
  union { uint32_t u; float f; } x; x.u = ((uint32_t)v) << 16; return x.f;
}
__device__ __forceinline__ u16 f2bf(float f) {
  union { float f; uint32_t u; } x; x.f = f;
  uint32_t u = x.u;
  return (u16)((u + 0x7fffu + ((u >> 16) & 1u)) >> 16);  // RNE
}
__device__ __forceinline__ void unp8(int4 r, float* f) {
  f[0] = __uint_as_float(((uint32_t)r.x) << 16);
  f[1] = __uint_as_float(((uint32_t)r.x) & 0xffff0000u);
  f[2] = __uint_as_float(((uint32_t)r.y) << 16);
  f[3] = __uint_as_float(((uint32_t)r.y) & 0xffff0000u);
  f[4] = __uint_as_float(((uint32_t)r.z) << 16);
  f[5] = __uint_as_float(((uint32_t)r.z) & 0xffff0000u);
  f[6] = __uint_as_float(((uint32_t)r.w) << 16);
  f[7] = __uint_as_float(((uint32_t)r.w) & 0xffff0000u);
}

// 16B global -> LDS async; lp MUST be wave-uniform (HW adds lane*16)
__device__ __forceinline__ void copy16(const u16* g, u16* l) {
#if defined(__has_builtin) && __has_builtin(__builtin_amdgcn_global_load_lds)
  uintptr_t li = (uintptr_t)l;
  uintptr_t gi = (uintptr_t)g;
  __builtin_amdgcn_global_load_lds((const __attribute__((address_space(1))) uint32_t*)gi,
                                   (__attribute__((address_space(3))) uint32_t*)li, 16, 0, 0);
#else
  *(int4*)l = *(const int4*)g;
#endif
}

// ---------------- K0: weight convert+transpose to bf16 [N][K] ----------------
__global__ __launch_bounds__(256) void k0_prep(const float* __restrict__ qkvw,
                                               const float* __restrict__ projw,
                                               const float* __restrict__ w1,
                                               const float* __restrict__ w2,
                                               u16* __restrict__ wbuf) {
  int idx = blockIdx.x * 256 + threadIdx.x;      // 786432 total
  if (idx < 196608) {                            // qkv_w (256,768) -> [768][256]
    int nn = idx >> 8, kk = idx & 255;
    wbuf[idx] = f2bf(qkvw[kk * 768 + nn]);
  } else if (idx < 262144) {                     // proj_w (256,256) -> [256][256]
    int i = idx - 196608; int nn = i >> 8, kk = i & 255;
    wbuf[idx] = f2bf(projw[kk * 256 + nn]);
  } else if (idx < 524288) {                     // ffn_w1 (256,1024) -> [1024][256]
    int i = idx - 262144; int nn = i >> 8, kk = i & 255;
    wbuf[idx] = f2bf(w1[kk * 1024 + nn]);
  } else {                                       // ffn_w2 (1024,256) -> [256][1024]
    int i = idx - 524288; int nn = i >> 10, kk = i & 1023;
    wbuf[idx] = f2bf(w2[kk * 256 + nn]);
  }
}

// ---------------- K1: LN1, one wave per row ----------------
__global__ __launch_bounds__(256) void k1_ln1(const float* __restrict__ x,
                                              const float* __restrict__ g,
                                              const float* __restrict__ b,
                                              u16* __restrict__ Y, int row0) {
  int t = threadIdx.x; int lr = t >> 6; int lane = t & 63;
  size_t row = (size_t)blockIdx.x * 4 + lr;
  const float4 xv = *(const float4*)&x[((size_t)row0 + row) * 256 + lane * 4];
  float s = xv.x + xv.y + xv.z + xv.w;
  float q = xv.x * xv.x + xv.y * xv.y + xv.z * xv.z + xv.w * xv.w;
  #pragma unroll
  for (int off = 32; off > 0; off >>= 1) { s += __shfl_xor(s, off); q += __shfl_xor(q, off); }
  float mean = s * (1.0f / 256.0f);
  float var  = q * (1.0f / 256.0f) - mean * mean;
  float rstd = rsqrtf(var + 1e-5f);
  const float4 gv = *(const float4*)&g[lane * 4];
  const float4 bv = *(const float4*)&b[lane * 4];
  float y0 = (xv.x - mean) * rstd * gv.x + bv.x;
  float y1 = (xv.y - mean) * rstd * gv.y + bv.y;
  float y2 = (xv.z - mean) * rstd * gv.z + bv.z;
  float y3 = (xv.w - mean) * rstd * gv.w + bv.w;
  uint2 r;
  r.x = (uint32_t)f2bf(y0) | ((uint32_t)f2bf(y1) << 16);
  r.y = (uint32_t)f2bf(y2) | ((uint32_t)f2bf(y3) << 16);
  *(uint2*)&Y[row * 256 + lane * 4] = r;
}

// ---------------- A-stationary GEMM: BM=64 rows, full K=256 in LDS ----------------
// C[64 x NB*128] = A[64][256] @ Bw[NB*128][256]^T (+bias, optional GELU), bf16 out.
// B fragments are loaded DIRECTLY from global (weights are L2-resident; no intra-block
// reuse to exploit), so the K-loop has no barriers at all.
template <int NB, bool GELU>
__global__ __launch_bounds__(256) void kA_gemm(const u16* __restrict__ A, const u16* __restrict__ Bw,
                                               const float* __restrict__ bias, u16* __restrict__ C) {
  __shared__ u16 Al[64 * 264];    // padded stride 264 (132 dw = 4 mod 32): staggered banks
  const int t = threadIdx.x, w = t >> 6, lane = t & 63, quad = lane >> 4, lrow = lane & 15;
  const int wm = w >> 1, wn = w & 1;
  const int mb = blockIdx.x * 64;
  #pragma unroll
  for (int r = 0; r < 8; r++) {                  // stage A once (regular stores: padded dst)
    int c = r * 256 + t;
    int row = c >> 5, col = (c & 31) * 8;
    int4 v = *(const int4*)&A[(size_t)(mb + row) * 256 + col];
    *(int4*)&Al[row * 264 + col] = v;
  }
  __syncthreads();
  constexpr int LDC = NB * 128;
  for (int nb = 0; nb < NB; nb++) {
    f32x4 acc[2][4];
    #pragma unroll
    for (int i = 0; i < 2; i++)
      #pragma unroll
      for (int j = 0; j < 4; j++) acc[i][j] = f32x4{0.f, 0.f, 0.f, 0.f};
    for (int kc = 0; kc < 8; kc++) {
      short8 af[2], bfr[4];
      #pragma unroll
      for (int nt = 0; nt < 4; nt++)
        bfr[nt] = *(const short8*)&Bw[(size_t)(nb * 128 + wn * 64 + nt * 16 + lrow) * 256 + kc * 32 + quad * 8];
      #pragma unroll
      for (int mt = 0; mt < 2; mt++)
        af[mt] = *(const short8*)&Al[(wm * 32 + mt * 16 + lrow) * 264 + kc * 32 + quad * 8];
      #pragma unroll
      for (int mt = 0; mt < 2; mt++)
        #pragma unroll
        for (int nt = 0; nt < 4; nt++)
          acc[mt][nt] = __builtin_amdgcn_mfma_f32_16x16x32_bf16(af[mt], bfr[nt], acc[mt][nt], 0, 0, 0);
    }
    #pragma unroll
    for (int nt = 0; nt < 4; nt++) {
      int n = nb * 128 + wn * 64 + nt * 16 + lrow;
      float bv = bias[n];
      #pragma unroll
      for (int mt = 0; mt < 2; mt++)
        #pragma unroll
        for (int i = 0; i < 4; i++) {
          int m = mb + wm * 32 + mt * 16 + quad * 4 + i;
          float u = acc[mt][nt][i] + bv;
          if (GELU) u = 0.5f * u * (1.0f + erff(u * 0.70710678118654752440f));
          C[(size_t)m * LDC + n] = f2bf(u);
        }
    }
  }
}

// ---------------- K3: cosine attention via MFMA ----------------
// One block = one n (25 rows). 4 waves x 2 heads. Per head:
//   S = mfma(Q_frag(raw, global), K_frag(raw, LDS, XOR-swizzled))  [2x2 tiles, K=32]
//   logits = S * fct[q] * invk[kr]   (norms/temperature folded in, C-layout col=kr=lane&15)
//   softmax over kr: 16-lane shfl_xor tree; P -> bf16 -> per-wave LDS bounce
//   O = mfma(P_frag, Vt_frag)  with V transposed once at staging (stride-40 rows, 16B aligned)
// Padding lanes (kr>=25, q>=25) are select-masked; V/invk pads zero-filled (NaN-safe).
__global__ __launch_bounds__(256) void k3_attn(const u16* __restrict__ QKV,
                                               const float* __restrict__ lscale,
                                               u16* __restrict__ O) {
  __shared__ u16 Kl[8192];         // [vr][256] chunk-XOR swizzled; rows 25..31 uninit (masked)
  __shared__ u16 Vt[10304];        // [h](stride 1288)[d](stride 40)[kr]; kr 25..31 zeroed
  __shared__ u16 Pl[4][1280];      // per-wave P: [q](stride 40)[kr]
  __shared__ float invk[256];      // [h][kr] 1/max(||k||,eps); kr 25..31 zeroed

  const int n = blockIdx.x;
  const int t = threadIdx.x;
  const int w = t >> 6, lane = t & 63, quad = lane >> 4, l15 = lane & 15;
  const size_t n25 = (size_t)n * 25;

  // ---- stage K: 800 16B chunks, source chunk XOR-swizzled so LDS is bank-balanced ----
  #pragma unroll
  for (int r = 0; r < 4; r++) {
    int c = r * 256 + t;
    if (c < 800) {
      int vr = c >> 5, ci = c & 31;
      const u16* gp = QKV + (n25 + vr) * 768 + 256 + (size_t)((ci ^ (vr & 7)) * 8);
      u16* lp = Kl + (size_t)(r * 256 + w * 64) * 8;          // wave-uniform base
      copy16(gp, lp);
    }
  }
  // ---- stage V transposed: coalesced int4 read -> 8 scattered b16 writes ----
  #pragma unroll
  for (int r = 0; r < 4; r++) {
    int c = r * 256 + t;
    if (c < 800) {
      int vr = c >> 5, ci = c & 31, h = ci >> 2, d8 = (ci & 3) * 8;
      int4 rv = *(const int4*)&QKV[(n25 + vr) * 768 + 512 + ci * 8];
      int base = h * 1288 + d8 * 40 + vr;
      Vt[base +   0] = (u16)((uint32_t)rv.x & 0xffffu);
      Vt[base +  40] = (u16)((uint32_t)rv.x >> 16);
      Vt[base +  80] = (u16)((uint32_t)rv.y & 0xffffu);
      Vt[base + 120] = (u16)((uint32_t)rv.y >> 16);
      Vt[base + 160] = (u16)((uint32_t)rv.z & 0xffffu);
      Vt[base + 200] = (u16)((uint32_t)rv.z >> 16);
      Vt[base + 240] = (u16)((uint32_t)rv.w & 0xffffu);
      Vt[base + 280] = (u16)((uint32_t)rv.w >> 16);
    }
  }
  // ---- zero Vt pad columns kr=25..31 (one (h,d) pair per thread) ----
  {
    int h = t >> 5, d = t & 31;
    int base = h * 1288 + d * 40 + 25;
    #pragma unroll
    for (int j = 0; j < 7; j++) Vt[base + j] = 0;
  }
  __syncthreads();

  // ---- per-row 1/||k|| (raw K stays in LDS; applied column-wise post-MFMA) ----
  if (t < 200) {
    int h = (t * 41) >> 10;                      // t/25 for t<200
    int vr = t - h * 25;
    float ss = 0.f;
    #pragma unroll
    for (int q = 0; q < 4; q++) {
      int chunk = (h * 4 + q) ^ (vr & 7);
      int4 rv = *(const int4*)&Kl[vr * 256 + chunk * 8];
      float f[8]; unp8(rv, f);
      #pragma unroll
      for (int j = 0; j < 8; j++) ss += f[j] * f[j];
    }
    invk[h * 32 + vr] = 1.0f / fmaxf(sqrtf(ss), 1e-12f);
  } else {                                       // zero pad entries kr=25..31 (56 slots)
    int u = t - 200;
    int h = (u * 37) >> 8;                       // u/7 for u<56
    int j = u - h * 7;
    invk[h * 32 + 25 + j] = 0.f;
  }
  __syncthreads();

  const u16* qbase = QKV + n25 * 768;
  const f32x4 zz = {0.f, 0.f, 0.f, 0.f};
  #pragma unroll
  for (int hh = 0; hh < 2; hh++) {
    const int h = w * 2 + hh;
    const float sc = expf(fminf(lscale[h], 4.6051701859880913680f));   // min(ls, ln 100)

    // --- QK^T: A = raw Q rows from global (q = l15 [+16]); B = raw K rows from LDS ---
    short8 af0 = *(const short8*)(qbase + (size_t)l15 * 768 + h * 32 + quad * 8);
    short8 af1 = *(const short8*)(qbase + (size_t)(16 + l15) * 768 + h * 32 + quad * 8);
    short8 bf0 = *(const short8*)&Kl[l15 * 256 + (((h * 4 + quad) ^ (l15 & 7)) * 8)];
    short8 bf1 = *(const short8*)&Kl[(16 + l15) * 256 + (((h * 4 + quad) ^ ((16 + l15) & 7)) * 8)];
    f32x4 sA[2][2];
    sA[0][0] = __builtin_amdgcn_mfma_f32_16x16x32_bf16(af0, bf0, zz, 0, 0, 0);
    sA[0][1] = __builtin_amdgcn_mfma_f32_16x16x32_bf16(af0, bf1, zz, 0, 0, 0);
    sA[1][0] = __builtin_amdgcn_mfma_f32_16x16x32_bf16(af1, bf0, zz, 0, 0, 0);
    sA[1][1] = __builtin_amdgcn_mfma_f32_16x16x32_bf16(af1, bf1, zz, 0, 0, 0);

    // --- per-q-row factor: sc / (max(||q||,eps)*sqrt(32)), from the raw fragment ---
    float ss0 = 0.f, ss1 = 0.f;
    #pragma unroll
    for (int j = 0; j < 8; j++) {
      float f0 = bf2f((u16)af0[j]); ss0 += f0 * f0;
      float f1 = bf2f((u16)af1[j]); ss1 += f1 * f1;
    }
    ss0 += __shfl_xor(ss0, 16); ss0 += __shfl_xor(ss0, 32);
    ss1 += __shfl_xor(ss1, 16); ss1 += __shfl_xor(ss1, 32);
    float fct0 = sc / (fmaxf(sqrtf(ss0), 1e-12f) * 5.6568542494923802f);
    float fct1 = sc / (fmaxf(sqrtf(ss1), 1e-12f) * 5.6568542494923802f);

    const float ik0 = invk[h * 32 + l15];        // kr = l15 (<25 always)
    const float ik1 = invk[h * 32 + 16 + l15];   // kr = 16+l15 (0 for pads)
    const bool v1 = l15 < 9;

    // --- softmax over kr (C layout: col = kr = lane&15, row = quad*4+i) ---
    #pragma unroll
    for (int qt = 0; qt < 2; qt++) {
      #pragma unroll
      for (int i = 0; i < 4; i++) {
        float fr = __shfl(qt == 0 ? fct0 : fct1, quad * 4 + i);
        float l0 = sA[qt][0][i] * fr * ik0;
        float l1 = sA[qt][1][i] * fr * ik1;
        float m = fmaxf(l0, v1 ? l1 : -1e30f);
        #pragma unroll
        for (int o = 1; o < 16; o <<= 1) m = fmaxf(m, __shfl_xor(m, o));
        float e0 = expf(l0 - m);
        float e1 = v1 ? expf(l1 - m) : 0.f;
        float se = e0 + e1;
        #pragma unroll
        for (int o = 1; o < 16; o <<= 1) se += __shfl_xor(se, o);
        float inv = 1.0f / se;
        int q = qt * 16 + quad * 4 + i;
        Pl[w][q * 40 + l15]      = f2bf(e0 * inv);
        Pl[w][q * 40 + 16 + l15] = f2bf(e1 * inv);
      }
    }

    // --- PV: A = P (LDS bounce), B = Vt (transposed V); K-dim = kr = 32 ---
    short8 pa0 = *(const short8*)&Pl[w][l15 * 40 + quad * 8];
    short8 pa1 = *(const short8*)&Pl[w][(16 + l15) * 40 + quad * 8];
    short8 vb0 = *(const short8*)&Vt[h * 1288 + l15 * 40 + quad * 8];
    short8 vb1 = *(const short8*)&Vt[h * 1288 + (16 + l15) * 40 + quad * 8];
    f32x4 oA[2][2];
    oA[0][0] = __builtin_amdgcn_mfma_f32_16x16x32_bf16(pa0, vb0, zz, 0, 0, 0);
    oA[0][1] = __builtin_amdgcn_mfma_f32_16x16x32_bf16(pa0, vb1, zz, 0, 0, 0);
    oA[1][0] = __builtin_amdgcn_mfma_f32_16x16x32_bf16(pa1, vb0, zz, 0, 0, 0);
    oA[1][1] = __builtin_amdgcn_mfma_f32_16x16x32_bf16(pa1, vb1, zz, 0, 0, 0);

    // --- store (col = d = lane&15 [+16], row = q = qt*16+quad*4+i; mask q<25) ---
    u16* ob = O + n25 * 256 + h * 32;
    #pragma unroll
    for (int qt = 0; qt < 2; qt++)
      #pragma unroll
      for (int i = 0; i < 4; i++) {
        int qr = quad * 4 + i;
        if (qt == 1 && qr >= 9) continue;
        int q = qt * 16 + qr;
        ob[(size_t)q * 256 + l15]      = f2bf(oA[qt][0][i]);
        ob[(size_t)q * 256 + 16 + l15] = f2bf(oA[qt][1][i]);
      }
  }
}

// ---------------- K4: xf = O@Wp + b + x; fused LN2 -> xf(bf16), y2(bf16) ----------------
// A (attention output, 64x256) staged once in padded LDS; B = proj_w direct from L2.
// No barriers in the K-loop.
__global__ __launch_bounds__(256) void k4_proj(const u16* __restrict__ A, const u16* __restrict__ Bw,
                                               const float* __restrict__ bias,
                                               const float* __restrict__ x,
                                               const float* __restrict__ g2, const float* __restrict__ b2,
                                               u16* __restrict__ xfb, u16* __restrict__ y2b, int row0) {
  __shared__ u16 Al[64 * 264];
  __shared__ float ps[4][64], pq[4][64], meanv[64], rstdv[64];
  const int t = threadIdx.x, w = t >> 6, lane = t & 63, quad = lane >> 4, lrow = lane & 15;
  const int wn = w;
  const int mb = blockIdx.x * 64;
  #pragma unroll
  for (int r = 0; r < 8; r++) {                  // stage A once
    int c = r * 256 + t;
    int row = c >> 5, col = (c & 31) * 8;
    int4 v = *(const int4*)&A[(size_t)(mb + row) * 256 + col];
    *(int4*)&Al[row * 264 + col] = v;
  }
  __syncthreads();
  f32x4 acc[4][4];
  #pragma unroll
  for (int i = 0; i < 4; i++)
    #pragma unroll
    for (int j = 0; j < 4; j++) acc[i][j] = f32x4{0.f, 0.f, 0.f, 0.f};
  for (int kc = 0; kc < 8; kc++) {
    short8 af[4], bfr[4];
    #pragma unroll
    for (int nt = 0; nt < 4; nt++)
      bfr[nt] = *(const short8*)&Bw[(size_t)(wn * 64 + nt * 16 + lrow) * 256 + kc * 32 + quad * 8];
    #pragma unroll
    for (int mt = 0; mt < 4; mt++)
      af[mt] = *(const short8*)&Al[(mt * 16 + lrow) * 264 + kc * 32 + quad * 8];
    #pragma unroll
    for (int mt = 0; mt < 4; mt++)
      #pragma unroll
      for (int nt = 0; nt < 4; nt++)
        acc[mt][nt] = __builtin_amdgcn_mfma_f32_16x16x32_bf16(af[mt], bfr[nt], acc[mt][nt], 0, 0, 0);
  }
  #pragma unroll
  for (int nt = 0; nt < 4; nt++) {
    int nn = wn * 64 + nt * 16 + lrow;
    float bv = bias[nn];
    #pragma unroll
    for (int mt = 0; mt < 4; mt++)
      #pragma unroll
      for (int i = 0; i < 4; i++) {
        int m = mb + mt * 16 + quad * 4 + i;
        acc[mt][nt][i] += bv + x[((size_t)row0 + m) * 256 + nn];
      }
  }
  #pragma unroll
  for (int mt = 0; mt < 4; mt++)
    #pragma unroll
    for (int i = 0; i < 4; i++) {
      float s = 0.f, q = 0.f;
      #pragma unroll
      for (int nt = 0; nt < 4; nt++) { float v = acc[mt][nt][i]; s += v; q += v * v; }
      #pragma unroll
      for (int off = 1; off < 16; off <<= 1) { s += __shfl_xor(s, off); q += __shfl_xor(q, off); }
      if (lrow == 0) { int r = mt * 16 + quad * 4 + i; ps[w][r] = s; pq[w][r] = q; }
    }
  __syncthreads();
  if (t < 64) {
    float s = ps[0][t] + ps[1][t] + ps[2][t] + ps[3][t];
    float q = pq[0][t] + pq[1][t] + pq[2][t] + pq[3][t];
    float mean = s * (1.0f / 256.0f);
    float var  = q * (1.0f / 256.0f) - mean * mean;
    meanv[t] = mean; rstdv[t] = rsqrtf(var + 1e-5f);
  }
  __syncthreads();
  #pragma unroll
  for (int nt = 0; nt < 4; nt++) {
    int nn = wn * 64 + nt * 16 + lrow;
    float gg = g2[nn], bb = b2[nn];
    #pragma unroll
    for (int mt = 0; mt < 4; mt++)
      #pragma unroll
      for (int i = 0; i < 4; i++) {
        int r = mt * 16 + quad * 4 + i;
        int m = mb + r;
        float xfv = acc[mt][nt][i];
        xfb[(size_t)m * 256 + nn] = f2bf(xfv);
        y2b[(size_t)m * 256 + nn] = f2bf((xfv - meanv[r]) * rstdv[r] * gg + bb);
      }
  }
}

// ---------------- K6: out = xf + G @ W2 + b2; A K-chunked in LDS, B direct from L2 ----------------
__global__ __launch_bounds__(256) void k6_ffn2(const u16* __restrict__ G, const u16* __restrict__ W2w,
                                               const float* __restrict__ bias,
                                               const u16* __restrict__ xfb,
                                               float* __restrict__ out, int row0) {
  __shared__ u16 Al[64 * 264];
  const int t = threadIdx.x, w = t >> 6, lane = t & 63, quad = lane >> 4, lrow = lane & 15;
  const int wn = w;
  const int mb = blockIdx.x * 64;
  f32x4 acc[4][4];
  #pragma unroll
  for (int i = 0; i < 4; i++)
    #pragma unroll
    for (int j = 0; j < 4; j++) acc[i][j] = f32x4{0.f, 0.f, 0.f, 0.f};
  for (int kch = 0; kch < 4; kch++) {
    __syncthreads();                             // previous chunk's reads done
    #pragma unroll
    for (int r = 0; r < 8; r++) {                // stage A chunk 64x256 (padded)
      int c = r * 256 + t;
      int row = c >> 5, col = (c & 31) * 8;
      int4 v = *(const int4*)&G[(size_t)(mb + row) * 1024 + kch * 256 + col];
      *(int4*)&Al[row * 264 + col] = v;
    }
    __syncthreads();
    for (int kc = 0; kc < 8; kc++) {
      short8 af[4], bfr[4];
      #pragma unroll
      for (int nt = 0; nt < 4; nt++)
        bfr[nt] = *(const short8*)&W2w[(size_t)(wn * 64 + nt * 16 + lrow) * 1024 + kch * 256 + kc * 32 + quad * 8];
      #pragma unroll
      for (int mt = 0; mt < 4; mt++)
        af[mt] = *(const short8*)&Al[(mt * 16 + lrow) * 264 + kc * 32 + quad * 8];
      #pragma unroll
      for (int mt = 0; mt < 4; mt++)
        #pragma unroll
        for (int nt = 0; nt < 4; nt++)
          acc[mt][nt] = __builtin_amdgcn_mfma_f32_16x16x32_bf16(af[mt], bfr[nt], acc[mt][nt], 0, 0, 0);
    }
  }
  #pragma unroll
  for (int nt = 0; nt < 4; nt++) {
    int n = wn * 64 + nt * 16 + lrow;
    float bv = bias[n];
    #pragma unroll
    for (int mt = 0; mt < 4; mt++)
      #pragma unroll
      for (int i = 0; i < 4; i++) {
        int m = mb + mt * 16 + quad * 4 + i;
        out[((size_t)row0 + m) * 256 + n] = acc[mt][nt][i] + bv + bf2f(xfb[(size_t)m * 256 + n]);
      }
  }
}

// ---------------- host ----------------
#define WEIGHT_BYTES 1572864ull

extern "C" void kernel_launch(void* const* d_in, const int* in_sizes, int n_in,
                              void* d_out, int out_size, void* d_ws, size_t ws_size,
                              hipStream_t stream) {
  const float* x     = (const float*)d_in[0];
  const float* ln1g  = (const float*)d_in[1];
  const float* ln1b  = (const float*)d_in[2];
  const float* qkvw  = (const float*)d_in[3];
  const float* qkvb  = (const float*)d_in[4];
  const float* projw = (const float*)d_in[5];
  const float* projb = (const float*)d_in[6];
  const float* lsc   = (const float*)d_in[7];
  const float* ln2g  = (const float*)d_in[8];
  const float* ln2b  = (const float*)d_in[9];
  const float* w1    = (const float*)d_in[10];
  const float* b1    = (const float*)d_in[11];
  const float* w2    = (const float*)d_in[12];
  const float* b2    = (const float*)d_in[13];
  float* out = (float*)d_out;
  char* wsb = (char*)d_ws;

  u16* wbuf = (u16*)wsb;
  u16* WQ = wbuf;             // [768][256]
  u16* WP = wbuf + 196608;    // [256][256]
  u16* W1 = wbuf + 262144;    // [1024][256]
  u16* W2 = wbuf + 524288;    // [256][1024]

  size_t avail = ws_size > WEIGHT_BYTES ? ws_size - WEIGHT_BYTES : 0;
  int nchunks = 64;
  for (int c = 1; c <= 64; c <<= 1) {
    size_t Rr = 204800u / (unsigned)c;
    if (Rr * 5632ull <= avail) { nchunks = c; break; }
  }
  const int R = 204800 / nchunks;
  char* cb = wsb + WEIGHT_BYTES;
  u16* Ybuf = (u16*)(cb);
  u16* QKVb = (u16*)(cb + (size_t)R * 512);
  u16* Obuf = (u16*)(cb + (size_t)R * 2048);
  u16* XFb  = (u16*)(cb + (size_t)R * 2560);
  u16* Y2b  = (u16*)(cb + (size_t)R * 3072);
  u16* Gbuf = (u16*)(cb + (size_t)R * 3584);

  k0_prep<<<3072, 256, 0, stream>>>(qkvw, projw, w1, w2, wbuf);
  for (int c = 0; c < nchunks; c++) {
    int row0 = c * R;
    k1_ln1<<<R / 4, 256, 0, stream>>>(x, ln1g, ln1b, Ybuf, row0);
    kA_gemm<6, false><<<R / 64, 256, 0, stream>>>(Ybuf, WQ, qkvb, QKVb);
    k3_attn<<<R / 25, 256, 0, stream>>>(QKVb, lsc, Obuf);
    k4_proj<<<R / 64, 256, 0, stream>>>(Obuf, WP, projb, x, ln2g, ln2b, XFb, Y2b, row0);
    kA_gemm<8, true><<<R / 64, 256, 0, stream>>>(Y2b, W1, b1, Gbuf);
    k6_ffn2<<<R / 64, 256, 0, stream>>>(Gbuf, W2, b2, XFb, out, row0);
  }
}

// Round 4
// 1635.679 us; speedup vs baseline: 1.1860x; 1.1860x over previous
//
#include <hip/hip_runtime.h>
#include <stdint.h>

typedef unsigned short u16;
typedef __attribute__((ext_vector_type(8))) short short8;
typedef __attribute__((ext_vector_type(4))) float f32x4;

// ---------------- numeric helpers ----------------
__device__ __forceinline__ float bf2f(u16 v) {
  union { uint32_t u; float f; } x; x.u = ((uint32_t)v) << 16; return x.f;
}
__device__ __forceinline__ u16 f2bf(float f) {
  union { float f; uint32_t u; } x; x.f = f;
  uint32_t u = x.u;
  return (u16)((u + 0x7fffu + ((u >> 16) & 1u)) >> 16);  // RNE
}
__device__ __forceinline__ void unp8(int4 r, float* f) {
  f[0] = __uint_as_float(((uint32_t)r.x) << 16);
  f[1] = __uint_as_float(((uint32_t)r.x) & 0xffff0000u);
  f[2] = __uint_as_float(((uint32_t)r.y) << 16);
  f[3] = __uint_as_float(((uint32_t)r.y) & 0xffff0000u);
  f[4] = __uint_as_float(((uint32_t)r.z) << 16);
  f[5] = __uint_as_float(((uint32_t)r.z) & 0xffff0000u);
  f[6] = __uint_as_float(((uint32_t)r.w) << 16);
  f[7] = __uint_as_float(((uint32_t)r.w) & 0xffff0000u);
}

// 16B global -> LDS async; lp MUST be wave-uniform (HW adds lane*16)
__device__ __forceinline__ void copy16(const u16* g, u16* l) {
#if defined(__has_builtin) && __has_builtin(__builtin_amdgcn_global_load_lds)
  uintptr_t li = (uintptr_t)l;
  uintptr_t gi = (uintptr_t)g;
  __builtin_amdgcn_global_load_lds((const __attribute__((address_space(1))) uint32_t*)gi,
                                   (__attribute__((address_space(3))) uint32_t*)li, 16, 0, 0);
#else
  *(int4*)l = *(const int4*)g;
#endif
}

// ---------------- K0: weight convert+transpose to bf16 [N][K] ----------------
__global__ __launch_bounds__(256) void k0_prep(const float* __restrict__ qkvw,
                                               const float* __restrict__ projw,
                                               const float* __restrict__ w1,
                                               const float* __restrict__ w2,
                                               u16* __restrict__ wbuf) {
  int idx = blockIdx.x * 256 + threadIdx.x;      // 786432 total
  if (idx < 196608) {                            // qkv_w (256,768) -> [768][256]
    int nn = idx >> 8, kk = idx & 255;
    wbuf[idx] = f2bf(qkvw[kk * 768 + nn]);
  } else if (idx < 262144) {                     // proj_w (256,256) -> [256][256]
    int i = idx - 196608; int nn = i >> 8, kk = i & 255;
    wbuf[idx] = f2bf(projw[kk * 256 + nn]);
  } else if (idx < 524288) {                     // ffn_w1 (256,1024) -> [1024][256]
    int i = idx - 262144; int nn = i >> 8, kk = i & 255;
    wbuf[idx] = f2bf(w1[kk * 1024 + nn]);
  } else {                                       // ffn_w2 (1024,256) -> [256][1024]
    int i = idx - 524288; int nn = i >> 10, kk = i & 1023;
    wbuf[idx] = f2bf(w2[kk * 256 + nn]);
  }
}

// ---------------- K1: LN1, one wave per row ----------------
__global__ __launch_bounds__(256) void k1_ln1(const float* __restrict__ x,
                                              const float* __restrict__ g,
                                              const float* __restrict__ b,
                                              u16* __restrict__ Y, int row0) {
  int t = threadIdx.x; int lr = t >> 6; int lane = t & 63;
  size_t row = (size_t)blockIdx.x * 4 + lr;
  const float4 xv = *(const float4*)&x[((size_t)row0 + row) * 256 + lane * 4];
  float s = xv.x + xv.y + xv.z + xv.w;
  float q = xv.x * xv.x + xv.y * xv.y + xv.z * xv.z + xv.w * xv.w;
  #pragma unroll
  for (int off = 32; off > 0; off >>= 1) { s += __shfl_xor(s, off); q += __shfl_xor(q, off); }
  float mean = s * (1.0f / 256.0f);
  float var  = q * (1.0f / 256.0f) - mean * mean;
  float rstd = rsqrtf(var + 1e-5f);
  const float4 gv = *(const float4*)&g[lane * 4];
  const float4 bv = *(const float4*)&b[lane * 4];
  float y0 = (xv.x - mean) * rstd * gv.x + bv.x;
  float y1 = (xv.y - mean) * rstd * gv.y + bv.y;
  float y2 = (xv.z - mean) * rstd * gv.z + bv.z;
  float y3 = (xv.w - mean) * rstd * gv.w + bv.w;
  uint2 r;
  r.x = (uint32_t)f2bf(y0) | ((uint32_t)f2bf(y1) << 16);
  r.y = (uint32_t)f2bf(y2) | ((uint32_t)f2bf(y3) << 16);
  *(uint2*)&Y[row * 256 + lane * 4] = r;
}

// ---------------- A-stationary GEMM, 2-phase double-buffered B staging ----------------
// C[64 x NB*128] = A[64][256] @ Bw[NB*128][256]^T (+bias, optional GELU), bf16 out.
// A: linear LDS, XOR-swizzled source (chunk ^= row&7) so fragment reads are bank-balanced.
// B: double-buffered 128x32 tiles; prefetch(j+1) issued BEFORE compute(j); one
// __syncthreads per iteration (vmcnt(0)+barrier) lands the prefetch.
template <int NB, bool GELU>
__global__ __launch_bounds__(256) void kA_gemm(const u16* __restrict__ A, const u16* __restrict__ Bw,
                                               const float* __restrict__ bias, u16* __restrict__ C) {
  __shared__ u16 Al[64 * 256];        // 32KB, swizzled
  __shared__ u16 Bl[2][128 * 32];     // 2x8KB
  const int t = threadIdx.x, w = t >> 6, lane = t & 63, quad = lane >> 4, lrow = lane & 15, l7 = lane & 7;
  const int wm = w >> 1, wn = w & 1;
  const int mb = blockIdx.x * 64;
  #pragma unroll
  for (int r = 0; r < 8; r++) {                  // stage A (async, swizzled source)
    int c = r * 256 + t;
    int row = c >> 5, q = (c & 31) ^ (row & 7);
    copy16(A + (size_t)(mb + row) * 256 + q * 8, Al + (size_t)(r * 256 + w * 64) * 8);
  }
  #pragma unroll
  for (int r = 0; r < 2; r++) {                  // stage B tile j=0 (nb=0,kc=0)
    int c = r * 256 + t;
    copy16(Bw + (size_t)(c >> 2) * 256 + (c & 3) * 8, Bl[0] + (size_t)(r * 256 + w * 64) * 8);
  }
  __syncthreads();                               // A + B0 ready
  constexpr int JMAX = NB * 8;
  constexpr int LDC = NB * 128;
  f32x4 acc[2][4];
  for (int j = 0; j < JMAX; j++) {
    const int nb = j >> 3, kc = j & 7;
    if (kc == 0) {
      #pragma unroll
      for (int i = 0; i < 2; i++)
        #pragma unroll
        for (int jj = 0; jj < 4; jj++) acc[i][jj] = f32x4{0.f, 0.f, 0.f, 0.f};
    }
    if (j + 1 < JMAX) {                          // prefetch next B tile into other buffer
      const int nb1 = (j + 1) >> 3, kc1 = (j + 1) & 7;
      u16* nxtB = Bl[(j + 1) & 1];
      #pragma unroll
      for (int r = 0; r < 2; r++) {
        int c = r * 256 + t;
        copy16(Bw + (size_t)(nb1 * 128 + (c >> 2)) * 256 + kc1 * 32 + (c & 3) * 8,
               nxtB + (size_t)(r * 256 + w * 64) * 8);
      }
    }
    const u16* curB = Bl[j & 1];
    short8 af[2], bfr[4];
    #pragma unroll
    for (int mt = 0; mt < 2; mt++) {
      int row = wm * 32 + mt * 16 + lrow;
      af[mt] = *(const short8*)&Al[row * 256 + (((kc * 4 + quad) ^ l7) * 8)];
    }
    #pragma unroll
    for (int nt = 0; nt < 4; nt++)
      bfr[nt] = *(const short8*)&curB[(wn * 64 + nt * 16 + lrow) * 32 + quad * 8];
    #pragma unroll
    for (int mt = 0; mt < 2; mt++)
      #pragma unroll
      for (int nt = 0; nt < 4; nt++)
        acc[mt][nt] = __builtin_amdgcn_mfma_f32_16x16x32_bf16(af[mt], bfr[nt], acc[mt][nt], 0, 0, 0);
    __syncthreads();                             // prefetch landed; all waves synced
    if (kc == 7) {
      #pragma unroll
      for (int nt = 0; nt < 4; nt++) {
        int n = nb * 128 + wn * 64 + nt * 16 + lrow;
        float bv = bias[n];
        #pragma unroll
        for (int mt = 0; mt < 2; mt++)
          #pragma unroll
          for (int i = 0; i < 4; i++) {
            int m = mb + wm * 32 + mt * 16 + quad * 4 + i;
            float u = acc[mt][nt][i] + bv;
            if (GELU) u = 0.5f * u * (1.0f + erff(u * 0.70710678118654752440f));
            C[(size_t)m * LDC + n] = f2bf(u);
          }
      }
    }
  }
}

// ---------------- K3: cosine attention via MFMA (unchanged, harness-verified) ----------------
__global__ __launch_bounds__(256) void k3_attn(const u16* __restrict__ QKV,
                                               const float* __restrict__ lscale,
                                               u16* __restrict__ O) {
  __shared__ u16 Kl[8192];         // [vr][256] chunk-XOR swizzled; rows 25..31 uninit (masked)
  __shared__ u16 Vt[10304];        // [h](stride 1288)[d](stride 40)[kr]; kr 25..31 zeroed
  __shared__ u16 Pl[4][1280];      // per-wave P: [q](stride 40)[kr]
  __shared__ float invk[256];      // [h][kr] 1/max(||k||,eps); kr 25..31 zeroed

  const int n = blockIdx.x;
  const int t = threadIdx.x;
  const int w = t >> 6, lane = t & 63, quad = lane >> 4, l15 = lane & 15;
  const size_t n25 = (size_t)n * 25;

  #pragma unroll
  for (int r = 0; r < 4; r++) {
    int c = r * 256 + t;
    if (c < 800) {
      int vr = c >> 5, ci = c & 31;
      const u16* gp = QKV + (n25 + vr) * 768 + 256 + (size_t)((ci ^ (vr & 7)) * 8);
      u16* lp = Kl + (size_t)(r * 256 + w * 64) * 8;          // wave-uniform base
      copy16(gp, lp);
    }
  }
  #pragma unroll
  for (int r = 0; r < 4; r++) {
    int c = r * 256 + t;
    if (c < 800) {
      int vr = c >> 5, ci = c & 31, h = ci >> 2, d8 = (ci & 3) * 8;
      int4 rv = *(const int4*)&QKV[(n25 + vr) * 768 + 512 + ci * 8];
      int base = h * 1288 + d8 * 40 + vr;
      Vt[base +   0] = (u16)((uint32_t)rv.x & 0xffffu);
      Vt[base +  40] = (u16)((uint32_t)rv.x >> 16);
      Vt[base +  80] = (u16)((uint32_t)rv.y & 0xffffu);
      Vt[base + 120] = (u16)((uint32_t)rv.y >> 16);
      Vt[base + 160] = (u16)((uint32_t)rv.z & 0xffffu);
      Vt[base + 200] = (u16)((uint32_t)rv.z >> 16);
      Vt[base + 240] = (u16)((uint32_t)rv.w & 0xffffu);
      Vt[base + 280] = (u16)((uint32_t)rv.w >> 16);
    }
  }
  {
    int h = t >> 5, d = t & 31;
    int base = h * 1288 + d * 40 + 25;
    #pragma unroll
    for (int j = 0; j < 7; j++) Vt[base + j] = 0;
  }
  __syncthreads();

  if (t < 200) {
    int h = (t * 41) >> 10;                      // t/25 for t<200
    int vr = t - h * 25;
    float ss = 0.f;
    #pragma unroll
    for (int q = 0; q < 4; q++) {
      int chunk = (h * 4 + q) ^ (vr & 7);
      int4 rv = *(const int4*)&Kl[vr * 256 + chunk * 8];
      float f[8]; unp8(rv, f);
      #pragma unroll
      for (int j = 0; j < 8; j++) ss += f[j] * f[j];
    }
    invk[h * 32 + vr] = 1.0f / fmaxf(sqrtf(ss), 1e-12f);
  } else {
    int u = t - 200;
    int h = (u * 37) >> 8;                       // u/7 for u<56
    int j = u - h * 7;
    invk[h * 32 + 25 + j] = 0.f;
  }
  __syncthreads();

  const u16* qbase = QKV + n25 * 768;
  const f32x4 zz = {0.f, 0.f, 0.f, 0.f};
  #pragma unroll
  for (int hh = 0; hh < 2; hh++) {
    const int h = w * 2 + hh;
    const float sc = expf(fminf(lscale[h], 4.6051701859880913680f));   // min(ls, ln 100)

    short8 af0 = *(const short8*)(qbase + (size_t)l15 * 768 + h * 32 + quad * 8);
    short8 af1 = *(const short8*)(qbase + (size_t)(16 + l15) * 768 + h * 32 + quad * 8);
    short8 bf0 = *(const short8*)&Kl[l15 * 256 + (((h * 4 + quad) ^ (l15 & 7)) * 8)];
    short8 bf1 = *(const short8*)&Kl[(16 + l15) * 256 + (((h * 4 + quad) ^ ((16 + l15) & 7)) * 8)];
    f32x4 sA[2][2];
    sA[0][0] = __builtin_amdgcn_mfma_f32_16x16x32_bf16(af0, bf0, zz, 0, 0, 0);
    sA[0][1] = __builtin_amdgcn_mfma_f32_16x16x32_bf16(af0, bf1, zz, 0, 0, 0);
    sA[1][0] = __builtin_amdgcn_mfma_f32_16x16x32_bf16(af1, bf0, zz, 0, 0, 0);
    sA[1][1] = __builtin_amdgcn_mfma_f32_16x16x32_bf16(af1, bf1, zz, 0, 0, 0);

    float ss0 = 0.f, ss1 = 0.f;
    #pragma unroll
    for (int j = 0; j < 8; j++) {
      float f0 = bf2f((u16)af0[j]); ss0 += f0 * f0;
      float f1 = bf2f((u16)af1[j]); ss1 += f1 * f1;
    }
    ss0 += __shfl_xor(ss0, 16); ss0 += __shfl_xor(ss0, 32);
    ss1 += __shfl_xor(ss1, 16); ss1 += __shfl_xor(ss1, 32);
    float fct0 = sc / (fmaxf(sqrtf(ss0), 1e-12f) * 5.6568542494923802f);
    float fct1 = sc / (fmaxf(sqrtf(ss1), 1e-12f) * 5.6568542494923802f);

    const float ik0 = invk[h * 32 + l15];
    const float ik1 = invk[h * 32 + 16 + l15];
    const bool v1 = l15 < 9;

    #pragma unroll
    for (int qt = 0; qt < 2; qt++) {
      #pragma unroll
      for (int i = 0; i < 4; i++) {
        float fr = __shfl(qt == 0 ? fct0 : fct1, quad * 4 + i);
        float l0 = sA[qt][0][i] * fr * ik0;
        float l1 = sA[qt][1][i] * fr * ik1;
        float m = fmaxf(l0, v1 ? l1 : -1e30f);
        #pragma unroll
        for (int o = 1; o < 16; o <<= 1) m = fmaxf(m, __shfl_xor(m, o));
        float e0 = expf(l0 - m);
        float e1 = v1 ? expf(l1 - m) : 0.f;
        float se = e0 + e1;
        #pragma unroll
        for (int o = 1; o < 16; o <<= 1) se += __shfl_xor(se, o);
        float inv = 1.0f / se;
        int q = qt * 16 + quad * 4 + i;
        Pl[w][q * 40 + l15]      = f2bf(e0 * inv);
        Pl[w][q * 40 + 16 + l15] = f2bf(e1 * inv);
      }
    }

    short8 pa0 = *(const short8*)&Pl[w][l15 * 40 + quad * 8];
    short8 pa1 = *(const short8*)&Pl[w][(16 + l15) * 40 + quad * 8];
    short8 vb0 = *(const short8*)&Vt[h * 1288 + l15 * 40 + quad * 8];
    short8 vb1 = *(const short8*)&Vt[h * 1288 + (16 + l15) * 40 + quad * 8];
    f32x4 oA[2][2];
    oA[0][0] = __builtin_amdgcn_mfma_f32_16x16x32_bf16(pa0, vb0, zz, 0, 0, 0);
    oA[0][1] = __builtin_amdgcn_mfma_f32_16x16x32_bf16(pa0, vb1, zz, 0, 0, 0);
    oA[1][0] = __builtin_amdgcn_mfma_f32_16x16x32_bf16(pa1, vb0, zz, 0, 0, 0);
    oA[1][1] = __builtin_amdgcn_mfma_f32_16x16x32_bf16(pa1, vb1, zz, 0, 0, 0);

    u16* ob = O + n25 * 256 + h * 32;
    #pragma unroll
    for (int qt = 0; qt < 2; qt++)
      #pragma unroll
      for (int i = 0; i < 4; i++) {
        int qr = quad * 4 + i;
        if (qt == 1 && qr >= 9) continue;
        int q = qt * 16 + qr;
        ob[(size_t)q * 256 + l15]      = f2bf(oA[qt][0][i]);
        ob[(size_t)q * 256 + 16 + l15] = f2bf(oA[qt][1][i]);
      }
  }
}

// ---------------- K4: xf = O@Wp + b + x; fused LN2 -> xf(bf16), y2(bf16) ----------------
// A staged once (swizzled copy16); B = proj_w, double-buffered 256x32 tiles, 2-phase.
__global__ __launch_bounds__(256) void k4_proj(const u16* __restrict__ A, const u16* __restrict__ Bw,
                                               const float* __restrict__ bias,
                                               const float* __restrict__ x,
                                               const float* __restrict__ g2, const float* __restrict__ b2,
                                               u16* __restrict__ xfb, u16* __restrict__ y2b, int row0) {
  __shared__ u16 Al[64 * 256];        // 32KB swizzled
  __shared__ u16 Bl[2][256 * 32];     // 2x16KB
  __shared__ float ps[4][64], pq[4][64], meanv[64], rstdv[64];
  const int t = threadIdx.x, w = t >> 6, lane = t & 63, quad = lane >> 4, lrow = lane & 15, l7 = lane & 7;
  const int wn = w;
  const int mb = blockIdx.x * 64;
  #pragma unroll
  for (int r = 0; r < 8; r++) {                  // stage A (async, swizzled)
    int c = r * 256 + t;
    int row = c >> 5, q = (c & 31) ^ (row & 7);
    copy16(A + (size_t)(mb + row) * 256 + q * 8, Al + (size_t)(r * 256 + w * 64) * 8);
  }
  #pragma unroll
  for (int r = 0; r < 4; r++) {                  // stage B tile kc=0
    int c = r * 256 + t;
    copy16(Bw + (size_t)(c >> 2) * 256 + (c & 3) * 8, Bl[0] + (size_t)(r * 256 + w * 64) * 8);
  }
  __syncthreads();
  f32x4 acc[4][4];
  #pragma unroll
  for (int i = 0; i < 4; i++)
    #pragma unroll
    for (int j = 0; j < 4; j++) acc[i][j] = f32x4{0.f, 0.f, 0.f, 0.f};
  for (int j = 0; j < 8; j++) {
    if (j + 1 < 8) {                             // prefetch next B tile
      u16* nxtB = Bl[(j + 1) & 1];
      #pragma unroll
      for (int r = 0; r < 4; r++) {
        int c = r * 256 + t;
        copy16(Bw + (size_t)(c >> 2) * 256 + (j + 1) * 32 + (c & 3) * 8,
               nxtB + (size_t)(r * 256 + w * 64) * 8);
      }
    }
    const u16* curB = Bl[j & 1];
    short8 af[4], bfr[4];
    #pragma unroll
    for (int mt = 0; mt < 4; mt++) {
      int row = mt * 16 + lrow;
      af[mt] = *(const short8*)&Al[row * 256 + (((j * 4 + quad) ^ l7) * 8)];
    }
    #pragma unroll
    for (int nt = 0; nt < 4; nt++)
      bfr[nt] = *(const short8*)&curB[(wn * 64 + nt * 16 + lrow) * 32 + quad * 8];
    #pragma unroll
    for (int mt = 0; mt < 4; mt++)
      #pragma unroll
      for (int nt = 0; nt < 4; nt++)
        acc[mt][nt] = __builtin_amdgcn_mfma_f32_16x16x32_bf16(af[mt], bfr[nt], acc[mt][nt], 0, 0, 0);
    __syncthreads();
  }
  #pragma unroll
  for (int nt = 0; nt < 4; nt++) {
    int nn = wn * 64 + nt * 16 + lrow;
    float bv = bias[nn];
    #pragma unroll
    for (int mt = 0; mt < 4; mt++)
      #pragma unroll
      for (int i = 0; i < 4; i++) {
        int m = mb + mt * 16 + quad * 4 + i;
        acc[mt][nt][i] += bv + x[((size_t)row0 + m) * 256 + nn];
      }
  }
  #pragma unroll
  for (int mt = 0; mt < 4; mt++)
    #pragma unroll
    for (int i = 0; i < 4; i++) {
      float s = 0.f, q = 0.f;
      #pragma unroll
      for (int nt = 0; nt < 4; nt++) { float v = acc[mt][nt][i]; s += v; q += v * v; }
      #pragma unroll
      for (int off = 1; off < 16; off <<= 1) { s += __shfl_xor(s, off); q += __shfl_xor(q, off); }
      if (lrow == 0) { int r = mt * 16 + quad * 4 + i; ps[w][r] = s; pq[w][r] = q; }
    }
  __syncthreads();
  if (t < 64) {
    float s = ps[0][t] + ps[1][t] + ps[2][t] + ps[3][t];
    float q = pq[0][t] + pq[1][t] + pq[2][t] + pq[3][t];
    float mean = s * (1.0f / 256.0f);
    float var  = q * (1.0f / 256.0f) - mean * mean;
    meanv[t] = mean; rstdv[t] = rsqrtf(var + 1e-5f);
  }
  __syncthreads();
  #pragma unroll
  for (int nt = 0; nt < 4; nt++) {
    int nn = wn * 64 + nt * 16 + lrow;
    float gg = g2[nn], bb = b2[nn];
    #pragma unroll
    for (int mt = 0; mt < 4; mt++)
      #pragma unroll
      for (int i = 0; i < 4; i++) {
        int r = mt * 16 + quad * 4 + i;
        int m = mb + r;
        float xfv = acc[mt][nt][i];
        xfb[(size_t)m * 256 + nn] = f2bf(xfv);
        y2b[(size_t)m * 256 + nn] = f2bf((xfv - meanv[r]) * rstdv[r] * gg + bb);
      }
  }
}

// ---------------- K6: out = xf + G @ W2 + b2; A kch-restaged (swizzled), B dbuf 2-phase ----------------
__global__ __launch_bounds__(256) void k6_ffn2(const u16* __restrict__ G, const u16* __restrict__ W2w,
                                               const float* __restrict__ bias,
                                               const u16* __restrict__ xfb,
                                               float* __restrict__ out, int row0) {
  __shared__ u16 Al[64 * 256];        // 32KB swizzled, restaged per kch
  __shared__ u16 Bl[2][256 * 32];     // 2x16KB
  const int t = threadIdx.x, w = t >> 6, lane = t & 63, quad = lane >> 4, lrow = lane & 15, l7 = lane & 7;
  const int wn = w;
  const int mb = blockIdx.x * 64;
  #pragma unroll
  for (int r = 0; r < 4; r++) {                  // stage B tile j=0 (kch=0,kc=0)
    int c = r * 256 + t;
    copy16(W2w + (size_t)(c >> 2) * 1024 + (c & 3) * 8, Bl[0] + (size_t)(r * 256 + w * 64) * 8);
  }
  f32x4 acc[4][4];
  #pragma unroll
  for (int i = 0; i < 4; i++)
    #pragma unroll
    for (int j = 0; j < 4; j++) acc[i][j] = f32x4{0.f, 0.f, 0.f, 0.f};
  for (int j = 0; j < 32; j++) {
    const int kch = j >> 3, kc = j & 7;
    if (kc == 0) {                               // restage A chunk (async, swizzled)
      #pragma unroll
      for (int r = 0; r < 8; r++) {
        int c = r * 256 + t;
        int row = c >> 5, q = (c & 31) ^ (row & 7);
        copy16(G + (size_t)(mb + row) * 1024 + kch * 256 + q * 8,
               Al + (size_t)(r * 256 + w * 64) * 8);
      }
      __syncthreads();                           // A (and, at j=0, B0) landed
    }
    if (j + 1 < 32) {                            // prefetch next B tile (in flight over MFMA)
      const int kch1 = (j + 1) >> 3, kc1 = (j + 1) & 7;
      u16* nxtB = Bl[(j + 1) & 1];
      #pragma unroll
      for (int r = 0; r < 4; r++) {
        int c = r * 256 + t;
        copy16(W2w + (size_t)(c >> 2) * 1024 + kch1 * 256 + kc1 * 32 + (c & 3) * 8,
               nxtB + (size_t)(r * 256 + w * 64) * 8);
      }
    }
    const u16* curB = Bl[j & 1];
    short8 af[4], bfr[4];
    #pragma unroll
    for (int mt = 0; mt < 4; mt++) {
      int row = mt * 16 + lrow;
      af[mt] = *(const short8*)&Al[row * 256 + (((kc * 4 + quad) ^ l7) * 8)];
    }
    #pragma unroll
    for (int nt = 0; nt < 4; nt++)
      bfr[nt] = *(const short8*)&curB[(wn * 64 + nt * 16 + lrow) * 32 + quad * 8];
    #pragma unroll
    for (int mt = 0; mt < 4; mt++)
      #pragma unroll
      for (int nt = 0; nt < 4; nt++)
        acc[mt][nt] = __builtin_amdgcn_mfma_f32_16x16x32_bf16(af[mt], bfr[nt], acc[mt][nt], 0, 0, 0);
    __syncthreads();
  }
  #pragma unroll
  for (int nt = 0; nt < 4; nt++) {
    int n = wn * 64 + nt * 16 + lrow;
    float bv = bias[n];
    #pragma unroll
    for (int mt = 0; mt < 4; mt++)
      #pragma unroll
      for (int i = 0; i < 4; i++) {
        int m = mb + mt * 16 + quad * 4 + i;
        out[((size_t)row0 + m) * 256 + n] = acc[mt][nt][i] + bv + bf2f(xfb[(size_t)m * 256 + n]);
      }
  }
}

// ---------------- host ----------------
#define WEIGHT_BYTES 1572864ull

extern "C" void kernel_launch(void* const* d_in, const int* in_sizes, int n_in,
                              void* d_out, int out_size, void* d_ws, size_t ws_size,
                              hipStream_t stream) {
  const float* x     = (const float*)d_in[0];
  const float* ln1g  = (const float*)d_in[1];
  const float* ln1b  = (const float*)d_in[2];
  const float* qkvw  = (const float*)d_in[3];
  const float* qkvb  = (const float*)d_in[4];
  const float* projw = (const float*)d_in[5];
  const float* projb = (const float*)d_in[6];
  const float* lsc   = (const float*)d_in[7];
  const float* ln2g  = (const float*)d_in[8];
  const float* ln2b  = (const float*)d_in[9];
  const float* w1    = (const float*)d_in[10];
  const float* b1    = (const float*)d_in[11];
  const float* w2    = (const float*)d_in[12];
  const float* b2    = (const float*)d_in[13];
  float* out = (float*)d_out;
  char* wsb = (char*)d_ws;

  u16* wbuf = (u16*)wsb;
  u16* WQ = wbuf;             // [768][256]
  u16* WP = wbuf + 196608;    // [256][256]
  u16* W1 = wbuf + 262144;    // [1024][256]
  u16* W2 = wbuf + 524288;    // [256][1024]

  size_t avail = ws_size > WEIGHT_BYTES ? ws_size - WEIGHT_BYTES : 0;
  int nchunks = 64;
  for (int c = 1; c <= 64; c <<= 1) {
    size_t Rr = 204800u / (unsigned)c;
    if (Rr * 5632ull <= avail) { nchunks = c; break; }
  }
  const int R = 204800 / nchunks;
  char* cb = wsb + WEIGHT_BYTES;
  u16* Ybuf = (u16*)(cb);
  u16* QKVb = (u16*)(cb + (size_t)R * 512);
  u16* Obuf = (u16*)(cb + (size_t)R * 2048);
  u16* XFb  = (u16*)(cb + (size_t)R * 2560);
  u16* Y2b  = (u16*)(cb + (size_t)R * 3072);
  u16* Gbuf = (u16*)(cb + (size_t)R * 3584);

  k0_prep<<<3072, 256, 0, stream>>>(qkvw, projw, w1, w2, wbuf);
  for (int c = 0; c < nchunks; c++) {
    int row0 = c * R;
    k1_ln1<<<R / 4, 256, 0, stream>>>(x, ln1g, ln1b, Ybuf, row0);
    kA_gemm<6, false><<<R / 64, 256, 0, stream>>>(Ybuf, WQ, qkvb, QKVb);
    k3_attn<<<R / 25, 256, 0, stream>>>(QKVb, lsc, Obuf);
    k4_proj<<<R / 64, 256, 0, stream>>>(Obuf, WP, projb, x, ln2g, ln2b, XFb, Y2b, row0);
    kA_gemm<8, true><<<R / 64, 256, 0, stream>>>(Y2b, W1, b1, Gbuf);
    k6_ffn2<<<R / 64, 256, 0, stream>>>(Gbuf, W2, b2, XFb, out, row0);
  }
}

// Round 6
// 1567.917 us; speedup vs baseline: 1.2373x; 1.0432x over previous
//
#include <hip/hip_runtime.h>
#include <stdint.h>

typedef unsigned short u16;
typedef __attribute__((ext_vector_type(8))) short short8;
typedef __attribute__((ext_vector_type(4))) float f32x4;

// ---------------- numeric helpers ----------------
__device__ __forceinline__ float bf2f(u16 v) {
  union { uint32_t u; float f; } x; x.u = ((uint32_t)v) << 16; return x.f;
}
__device__ __forceinline__ u16 f2bf(float f) {
  union { float f; uint32_t u; } x; x.f = f;
  uint32_t u = x.u;
  return (u16)((u + 0x7fffu + ((u >> 16) & 1u)) >> 16);  // RNE
}
__device__ __forceinline__ void unp8(int4 r, float* f) {
  f[0] = __uint_as_float(((uint32_t)r.x) << 16);
  f[1] = __uint_as_float(((uint32_t)r.x) & 0xffff0000u);
  f[2] = __uint_as_float(((uint32_t)r.y) << 16);
  f[3] = __uint_as_float(((uint32_t)r.y) & 0xffff0000u);
  f[4] = __uint_as_float(((uint32_t)r.z) << 16);
  f[5] = __uint_as_float(((uint32_t)r.z) & 0xffff0000u);
  f[6] = __uint_as_float(((uint32_t)r.w) << 16);
  f[7] = __uint_as_float(((uint32_t)r.w) & 0xffff0000u);
}

// tanh-form GELU: g = u - u * rcp(exp2(C*u*(1+0.044715*u^2)) + 1),
// C = 2*0.7978845608*log2(e) = 2.3022082. Max |err| vs erf-GELU ~2e-4 for |u|<3
// (hidden activations here: sigma~0.32). Branch-free; exact at +/-inf (no NaN:
// rcp(inf)=0 -> g=u; rcp(1)=1 -> g=0).
#if defined(__has_builtin) && __has_builtin(__builtin_amdgcn_exp2f)
#define EXP2F(x) __builtin_amdgcn_exp2f(x)
#else
#define EXP2F(x) exp2f(x)
#endif
#if defined(__has_builtin) && __has_builtin(__builtin_amdgcn_rcpf)
#define RCPF(x) __builtin_amdgcn_rcpf(x)
#else
#define RCPF(x) (1.0f / (x))
#endif
__device__ __forceinline__ float gelu_f(float u) {
  float e = EXP2F(u * fmaf(0.044715f * u, u, 1.0f) * 2.3022082f);
  return u - u * RCPF(e + 1.0f);
}

// 16B global -> LDS async; lp MUST be wave-uniform (HW adds lane*16)
__device__ __forceinline__ void copy16(const u16* g, u16* l) {
#if defined(__has_builtin) && __has_builtin(__builtin_amdgcn_global_load_lds)
  uintptr_t li = (uintptr_t)l;
  uintptr_t gi = (uintptr_t)g;
  __builtin_amdgcn_global_load_lds((const __attribute__((address_space(1))) uint32_t*)gi,
                                   (__attribute__((address_space(3))) uint32_t*)li, 16, 0, 0);
#else
  *(int4*)l = *(const int4*)g;
#endif
}

// ---------------- K0: weight convert+transpose to bf16 [N][K] ----------------
__global__ __launch_bounds__(256) void k0_prep(const float* __restrict__ qkvw,
                                               const float* __restrict__ projw,
                                               const float* __restrict__ w1,
                                               const float* __restrict__ w2,
                                               u16* __restrict__ wbuf) {
  int idx = blockIdx.x * 256 + threadIdx.x;      // 786432 total
  if (idx < 196608) {                            // qkv_w (256,768) -> [768][256]
    int nn = idx >> 8, kk = idx & 255;
    wbuf[idx] = f2bf(qkvw[kk * 768 + nn]);
  } else if (idx < 262144) {                     // proj_w (256,256) -> [256][256]
    int i = idx - 196608; int nn = i >> 8, kk = i & 255;
    wbuf[idx] = f2bf(projw[kk * 256 + nn]);
  } else if (idx < 524288) {                     // ffn_w1 (256,1024) -> [1024][256]
    int i = idx - 262144; int nn = i >> 8, kk = i & 255;
    wbuf[idx] = f2bf(w1[kk * 1024 + nn]);
  } else {                                       // ffn_w2 (1024,256) -> [256][1024]
    int i = idx - 524288; int nn = i >> 10, kk = i & 1023;
    wbuf[idx] = f2bf(w2[kk * 256 + nn]);
  }
}

// ---------------- K1: LN1, one wave per row ----------------
__global__ __launch_bounds__(256) void k1_ln1(const float* __restrict__ x,
                                              const float* __restrict__ g,
                                              const float* __restrict__ b,
                                              u16* __restrict__ Y, int row0) {
  int t = threadIdx.x; int lr = t >> 6; int lane = t & 63;
  size_t row = (size_t)blockIdx.x * 4 + lr;
  const float4 xv = *(const float4*)&x[((size_t)row0 + row) * 256 + lane * 4];
  float s = xv.x + xv.y + xv.z + xv.w;
  float q = xv.x * xv.x + xv.y * xv.y + xv.z * xv.z + xv.w * xv.w;
  #pragma unroll
  for (int off = 32; off > 0; off >>= 1) { s += __shfl_xor(s, off); q += __shfl_xor(q, off); }
  float mean = s * (1.0f / 256.0f);
  float var  = q * (1.0f / 256.0f) - mean * mean;
  float rstd = rsqrtf(var + 1e-5f);
  const float4 gv = *(const float4*)&g[lane * 4];
  const float4 bv = *(const float4*)&b[lane * 4];
  float y0 = (xv.x - mean) * rstd * gv.x + bv.x;
  float y1 = (xv.y - mean) * rstd * gv.y + bv.y;
  float y2 = (xv.z - mean) * rstd * gv.z + bv.z;
  float y3 = (xv.w - mean) * rstd * gv.w + bv.w;
  uint2 r;
  r.x = (uint32_t)f2bf(y0) | ((uint32_t)f2bf(y1) << 16);
  r.y = (uint32_t)f2bf(y2) | ((uint32_t)f2bf(y3) << 16);
  *(uint2*)&Y[row * 256 + lane * 4] = r;
}

// ---------------- A-stationary GEMM, 2-phase double-buffered B staging ----------------
// C[64 x NB*128] = A[64][256] @ Bw[NB*128][256]^T (+bias, optional GELU), bf16 out.
// A: linear LDS, XOR-swizzled source (chunk ^= row&7) so fragment reads are bank-balanced.
// B: double-buffered 128x32 tiles; prefetch(j+1) issued BEFORE compute(j); one
// __syncthreads per iteration (vmcnt(0)+barrier) lands the prefetch.
template <int NB, bool GELU>
__global__ __launch_bounds__(256) void kA_gemm(const u16* __restrict__ A, const u16* __restrict__ Bw,
                                               const float* __restrict__ bias, u16* __restrict__ C) {
  __shared__ u16 Al[64 * 256];        // 32KB, swizzled
  __shared__ u16 Bl[2][128 * 32];     // 2x8KB
  const int t = threadIdx.x, w = t >> 6, lane = t & 63, quad = lane >> 4, lrow = lane & 15, l7 = lane & 7;
  const int wm = w >> 1, wn = w & 1;
  const int mb = blockIdx.x * 64;
  #pragma unroll
  for (int r = 0; r < 8; r++) {                  // stage A (async, swizzled source)
    int c = r * 256 + t;
    int row = c >> 5, q = (c & 31) ^ (row & 7);
    copy16(A + (size_t)(mb + row) * 256 + q * 8, Al + (size_t)(r * 256 + w * 64) * 8);
  }
  #pragma unroll
  for (int r = 0; r < 2; r++) {                  // stage B tile j=0 (nb=0,kc=0)
    int c = r * 256 + t;
    copy16(Bw + (size_t)(c >> 2) * 256 + (c & 3) * 8, Bl[0] + (size_t)(r * 256 + w * 64) * 8);
  }
  __syncthreads();                               // A + B0 ready
  constexpr int JMAX = NB * 8;
  constexpr int LDC = NB * 128;
  f32x4 acc[2][4];
  for (int j = 0; j < JMAX; j++) {
    const int nb = j >> 3, kc = j & 7;
    if (kc == 0) {
      #pragma unroll
      for (int i = 0; i < 2; i++)
        #pragma unroll
        for (int jj = 0; jj < 4; jj++) acc[i][jj] = f32x4{0.f, 0.f, 0.f, 0.f};
    }
    if (j + 1 < JMAX) {                          // prefetch next B tile into other buffer
      const int nb1 = (j + 1) >> 3, kc1 = (j + 1) & 7;
      u16* nxtB = Bl[(j + 1) & 1];
      #pragma unroll
      for (int r = 0; r < 2; r++) {
        int c = r * 256 + t;
        copy16(Bw + (size_t)(nb1 * 128 + (c >> 2)) * 256 + kc1 * 32 + (c & 3) * 8,
               nxtB + (size_t)(r * 256 + w * 64) * 8);
      }
    }
    const u16* curB = Bl[j & 1];
    short8 af[2], bfr[4];
    #pragma unroll
    for (int mt = 0; mt < 2; mt++) {
      int row = wm * 32 + mt * 16 + lrow;
      af[mt] = *(const short8*)&Al[row * 256 + (((kc * 4 + quad) ^ l7) * 8)];
    }
    #pragma unroll
    for (int nt = 0; nt < 4; nt++)
      bfr[nt] = *(const short8*)&curB[(wn * 64 + nt * 16 + lrow) * 32 + quad * 8];
    #pragma unroll
    for (int mt = 0; mt < 2; mt++)
      #pragma unroll
      for (int nt = 0; nt < 4; nt++)
        acc[mt][nt] = __builtin_amdgcn_mfma_f32_16x16x32_bf16(af[mt], bfr[nt], acc[mt][nt], 0, 0, 0);
    __syncthreads();                             // prefetch landed; all waves synced
    if (kc == 7) {
      #pragma unroll
      for (int nt = 0; nt < 4; nt++) {
        int n = nb * 128 + wn * 64 + nt * 16 + lrow;
        float bv = bias[n];
        #pragma unroll
        for (int mt = 0; mt < 2; mt++)
          #pragma unroll
          for (int i = 0; i < 4; i++) {
            int m = mb + wm * 32 + mt * 16 + quad * 4 + i;
            float u = acc[mt][nt][i] + bv;
            if (GELU) u = gelu_f(u);
            C[(size_t)m * LDC + n] = f2bf(u);
          }
      }
    }
  }
}

// ---------------- K3: cosine attention via MFMA (unchanged, harness-verified) ----------------
__global__ __launch_bounds__(256) void k3_attn(const u16* __restrict__ QKV,
                                               const float* __restrict__ lscale,
                                               u16* __restrict__ O) {
  __shared__ u16 Kl[8192];         // [vr][256] chunk-XOR swizzled; rows 25..31 uninit (masked)
  __shared__ u16 Vt[10304];        // [h](stride 1288)[d](stride 40)[kr]; kr 25..31 zeroed
  __shared__ u16 Pl[4][1280];      // per-wave P: [q](stride 40)[kr]
  __shared__ float invk[256];      // [h][kr] 1/max(||k||,eps); kr 25..31 zeroed

  const int n = blockIdx.x;
  const int t = threadIdx.x;
  const int w = t >> 6, lane = t & 63, quad = lane >> 4, l15 = lane & 15;
  const size_t n25 = (size_t)n * 25;

  #pragma unroll
  for (int r = 0; r < 4; r++) {
    int c = r * 256 + t;
    if (c < 800) {
      int vr = c >> 5, ci = c & 31;
      const u16* gp = QKV + (n25 + vr) * 768 + 256 + (size_t)((ci ^ (vr & 7)) * 8);
      u16* lp = Kl + (size_t)(r * 256 + w * 64) * 8;          // wave-uniform base
      copy16(gp, lp);
    }
  }
  #pragma unroll
  for (int r = 0; r < 4; r++) {
    int c = r * 256 + t;
    if (c < 800) {
      int vr = c >> 5, ci = c & 31, h = ci >> 2, d8 = (ci & 3) * 8;
      int4 rv = *(const int4*)&QKV[(n25 + vr) * 768 + 512 + ci * 8];
      int base = h * 1288 + d8 * 40 + vr;
      Vt[base +   0] = (u16)((uint32_t)rv.x & 0xffffu);
      Vt[base +  40] = (u16)((uint32_t)rv.x >> 16);
      Vt[base +  80] = (u16)((uint32_t)rv.y & 0xffffu);
      Vt[base + 120] = (u16)((uint32_t)rv.y >> 16);
      Vt[base + 160] = (u16)((uint32_t)rv.z & 0xffffu);
      Vt[base + 200] = (u16)((uint32_t)rv.z >> 16);
      Vt[base + 240] = (u16)((uint32_t)rv.w & 0xffffu);
      Vt[base + 280] = (u16)((uint32_t)rv.w >> 16);
    }
  }
  {
    int h = t >> 5, d = t & 31;
    int base = h * 1288 + d * 40 + 25;
    #pragma unroll
    for (int j = 0; j < 7; j++) Vt[base + j] = 0;
  }
  __syncthreads();

  if (t < 200) {
    int h = (t * 41) >> 10;                      // t/25 for t<200
    int vr = t - h * 25;
    float ss = 0.f;
    #pragma unroll
    for (int q = 0; q < 4; q++) {
      int chunk = (h * 4 + q) ^ (vr & 7);
      int4 rv = *(const int4*)&Kl[vr * 256 + chunk * 8];
      float f[8]; unp8(rv, f);
      #pragma unroll
      for (int j = 0; j < 8; j++) ss += f[j] * f[j];
    }
    invk[h * 32 + vr] = 1.0f / fmaxf(sqrtf(ss), 1e-12f);
  } else {
    int u = t - 200;
    int h = (u * 37) >> 8;                       // u/7 for u<56
    int j = u - h * 7;
    invk[h * 32 + 25 + j] = 0.f;
  }
  __syncthreads();

  const u16* qbase = QKV + n25 * 768;
  const f32x4 zz = {0.f, 0.f, 0.f, 0.f};
  #pragma unroll
  for (int hh = 0; hh < 2; hh++) {
    const int h = w * 2 + hh;
    const float sc = expf(fminf(lscale[h], 4.6051701859880913680f));   // min(ls, ln 100)

    short8 af0 = *(const short8*)(qbase + (size_t)l15 * 768 + h * 32 + quad * 8);
    short8 af1 = *(const short8*)(qbase + (size_t)(16 + l15) * 768 + h * 32 + quad * 8);
    short8 bf0 = *(const short8*)&Kl[l15 * 256 + (((h * 4 + quad) ^ (l15 & 7)) * 8)];
    short8 bf1 = *(const short8*)&Kl[(16 + l15) * 256 + (((h * 4 + quad) ^ ((16 + l15) & 7)) * 8)];
    f32x4 sA[2][2];
    sA[0][0] = __builtin_amdgcn_mfma_f32_16x16x32_bf16(af0, bf0, zz, 0, 0, 0);
    sA[0][1] = __builtin_amdgcn_mfma_f32_16x16x32_bf16(af0, bf1, zz, 0, 0, 0);
    sA[1][0] = __builtin_amdgcn_mfma_f32_16x16x32_bf16(af1, bf0, zz, 0, 0, 0);
    sA[1][1] = __builtin_amdgcn_mfma_f32_16x16x32_bf16(af1, bf1, zz, 0, 0, 0);

    float ss0 = 0.f, ss1 = 0.f;
    #pragma unroll
    for (int j = 0; j < 8; j++) {
      float f0 = bf2f((u16)af0[j]); ss0 += f0 * f0;
      float f1 = bf2f((u16)af1[j]); ss1 += f1 * f1;
    }
    ss0 += __shfl_xor(ss0, 16); ss0 += __shfl_xor(ss0, 32);
    ss1 += __shfl_xor(ss1, 16); ss1 += __shfl_xor(ss1, 32);
    float fct0 = sc / (fmaxf(sqrtf(ss0), 1e-12f) * 5.6568542494923802f);
    float fct1 = sc / (fmaxf(sqrtf(ss1), 1e-12f) * 5.6568542494923802f);

    const float ik0 = invk[h * 32 + l15];
    const float ik1 = invk[h * 32 + 16 + l15];
    const bool v1 = l15 < 9;

    #pragma unroll
    for (int qt = 0; qt < 2; qt++) {
      #pragma unroll
      for (int i = 0; i < 4; i++) {
        float fr = __shfl(qt == 0 ? fct0 : fct1, quad * 4 + i);
        float l0 = sA[qt][0][i] * fr * ik0;
        float l1 = sA[qt][1][i] * fr * ik1;
        float m = fmaxf(l0, v1 ? l1 : -1e30f);
        #pragma unroll
        for (int o = 1; o < 16; o <<= 1) m = fmaxf(m, __shfl_xor(m, o));
        float e0 = expf(l0 - m);
        float e1 = v1 ? expf(l1 - m) : 0.f;
        float se = e0 + e1;
        #pragma unroll
        for (int o = 1; o < 16; o <<= 1) se += __shfl_xor(se, o);
        float inv = 1.0f / se;
        int q = qt * 16 + quad * 4 + i;
        Pl[w][q * 40 + l15]      = f2bf(e0 * inv);
        Pl[w][q * 40 + 16 + l15] = f2bf(e1 * inv);
      }
    }

    short8 pa0 = *(const short8*)&Pl[w][l15 * 40 + quad * 8];
    short8 pa1 = *(const short8*)&Pl[w][(16 + l15) * 40 + quad * 8];
    short8 vb0 = *(const short8*)&Vt[h * 1288 + l15 * 40 + quad * 8];
    short8 vb1 = *(const short8*)&Vt[h * 1288 + (16 + l15) * 40 + quad * 8];
    f32x4 oA[2][2];
    oA[0][0] = __builtin_amdgcn_mfma_f32_16x16x32_bf16(pa0, vb0, zz, 0, 0, 0);
    oA[0][1] = __builtin_amdgcn_mfma_f32_16x16x32_bf16(pa0, vb1, zz, 0, 0, 0);
    oA[1][0] = __builtin_amdgcn_mfma_f32_16x16x32_bf16(pa1, vb0, zz, 0, 0, 0);
    oA[1][1] = __builtin_amdgcn_mfma_f32_16x16x32_bf16(pa1, vb1, zz, 0, 0, 0);

    u16* ob = O + n25 * 256 + h * 32;
    #pragma unroll
    for (int qt = 0; qt < 2; qt++)
      #pragma unroll
      for (int i = 0; i < 4; i++) {
        int qr = quad * 4 + i;
        if (qt == 1 && qr >= 9) continue;
        int q = qt * 16 + qr;
        ob[(size_t)q * 256 + l15]      = f2bf(oA[qt][0][i]);
        ob[(size_t)q * 256 + 16 + l15] = f2bf(oA[qt][1][i]);
      }
  }
}

// ---------------- K4: xf = O@Wp + b + x; fused LN2 -> xf(bf16), y2(bf16) ----------------
// A staged once (swizzled copy16); B = proj_w, double-buffered 256x32 tiles, 2-phase.
__global__ __launch_bounds__(256) void k4_proj(const u16* __restrict__ A, const u16* __restrict__ Bw,
                                               const float* __restrict__ bias,
                                               const float* __restrict__ x,
                                               const float* __restrict__ g2, const float* __restrict__ b2,
                                               u16* __restrict__ xfb, u16* __restrict__ y2b, int row0) {
  __shared__ u16 Al[64 * 256];        // 32KB swizzled
  __shared__ u16 Bl[2][256 * 32];     // 2x16KB
  __shared__ float ps[4][64], pq[4][64], meanv[64], rstdv[64];
  const int t = threadIdx.x, w = t >> 6, lane = t & 63, quad = lane >> 4, lrow = lane & 15, l7 = lane & 7;
  const int wn = w;
  const int mb = blockIdx.x * 64;
  #pragma unroll
  for (int r = 0; r < 8; r++) {                  // stage A (async, swizzled)
    int c = r * 256 + t;
    int row = c >> 5, q = (c & 31) ^ (row & 7);
    copy16(A + (size_t)(mb + row) * 256 + q * 8, Al + (size_t)(r * 256 + w * 64) * 8);
  }
  #pragma unroll
  for (int r = 0; r < 4; r++) {                  // stage B tile kc=0
    int c = r * 256 + t;
    copy16(Bw + (size_t)(c >> 2) * 256 + (c & 3) * 8, Bl[0] + (size_t)(r * 256 + w * 64) * 8);
  }
  __syncthreads();
  f32x4 acc[4][4];
  #pragma unroll
  for (int i = 0; i < 4; i++)
    #pragma unroll
    for (int j = 0; j < 4; j++) acc[i][j] = f32x4{0.f, 0.f, 0.f, 0.f};
  for (int j = 0; j < 8; j++) {
    if (j + 1 < 8) {                             // prefetch next B tile
      u16* nxtB = Bl[(j + 1) & 1];
      #pragma unroll
      for (int r = 0; r < 4; r++) {
        int c = r * 256 + t;
        copy16(Bw + (size_t)(c >> 2) * 256 + (j + 1) * 32 + (c & 3) * 8,
               nxtB + (size_t)(r * 256 + w * 64) * 8);
      }
    }
    const u16* curB = Bl[j & 1];
    short8 af[4], bfr[4];
    #pragma unroll
    for (int mt = 0; mt < 4; mt++) {
      int row = mt * 16 + lrow;
      af[mt] = *(const short8*)&Al[row * 256 + (((j * 4 + quad) ^ l7) * 8)];
    }
    #pragma unroll
    for (int nt = 0; nt < 4; nt++)
      bfr[nt] = *(const short8*)&curB[(wn * 64 + nt * 16 + lrow) * 32 + quad * 8];
    #pragma unroll
    for (int mt = 0; mt < 4; mt++)
      #pragma unroll
      for (int nt = 0; nt < 4; nt++)
        acc[mt][nt] = __builtin_amdgcn_mfma_f32_16x16x32_bf16(af[mt], bfr[nt], acc[mt][nt], 0, 0, 0);
    __syncthreads();
  }
  #pragma unroll
  for (int nt = 0; nt < 4; nt++) {
    int nn = wn * 64 + nt * 16 + lrow;
    float bv = bias[nn];
    #pragma unroll
    for (int mt = 0; mt < 4; mt++)
      #pragma unroll
      for (int i = 0; i < 4; i++) {
        int m = mb + mt * 16 + quad * 4 + i;
        acc[mt][nt][i] += bv + x[((size_t)row0 + m) * 256 + nn];
      }
  }
  #pragma unroll
  for (int mt = 0; mt < 4; mt++)
    #pragma unroll
    for (int i = 0; i < 4; i++) {
      float s = 0.f, q = 0.f;
      #pragma unroll
      for (int nt = 0; nt < 4; nt++) { float v = acc[mt][nt][i]; s += v; q += v * v; }
      #pragma unroll
      for (int off = 1; off < 16; off <<= 1) { s += __shfl_xor(s, off); q += __shfl_xor(q, off); }
      if (lrow == 0) { int r = mt * 16 + quad * 4 + i; ps[w][r] = s; pq[w][r] = q; }
    }
  __syncthreads();
  if (t < 64) {
    float s = ps[0][t] + ps[1][t] + ps[2][t] + ps[3][t];
    float q = pq[0][t] + pq[1][t] + pq[2][t] + pq[3][t];
    float mean = s * (1.0f / 256.0f);
    float var  = q * (1.0f / 256.0f) - mean * mean;
    meanv[t] = mean; rstdv[t] = rsqrtf(var + 1e-5f);
  }
  __syncthreads();
  #pragma unroll
  for (int nt = 0; nt < 4; nt++) {
    int nn = wn * 64 + nt * 16 + lrow;
    float gg = g2[nn], bb = b2[nn];
    #pragma unroll
    for (int mt = 0; mt < 4; mt++)
      #pragma unroll
      for (int i = 0; i < 4; i++) {
        int r = mt * 16 + quad * 4 + i;
        int m = mb + r;
        float xfv = acc[mt][nt][i];
        xfb[(size_t)m * 256 + nn] = f2bf(xfv);
        y2b[(size_t)m * 256 + nn] = f2bf((xfv - meanv[r]) * rstdv[r] * gg + bb);
      }
  }
}

// ---------------- K6: out = xf + G @ W2 + b2; A kch-restaged (swizzled), B dbuf 2-phase ----------------
__global__ __launch_bounds__(256) void k6_ffn2(const u16* __restrict__ G, const u16* __restrict__ W2w,
                                               const float* __restrict__ bias,
                                               const u16* __restrict__ xfb,
                                               float* __restrict__ out, int row0) {
  __shared__ u16 Al[64 * 256];        // 32KB swizzled, restaged per kch
  __shared__ u16 Bl[2][256 * 32];     // 2x16KB
  const int t = threadIdx.x, w = t >> 6, lane = t & 63, quad = lane >> 4, lrow = lane & 15, l7 = lane & 7;
  const int wn = w;
  const int mb = blockIdx.x * 64;
  #pragma unroll
  for (int r = 0; r < 4; r++) {                  // stage B tile j=0 (kch=0,kc=0)
    int c = r * 256 + t;
    copy16(W2w + (size_t)(c >> 2) * 1024 + (c & 3) * 8, Bl[0] + (size_t)(r * 256 + w * 64) * 8);
  }
  f32x4 acc[4][4];
  #pragma unroll
  for (int i = 0; i < 4; i++)
    #pragma unroll
    for (int j = 0; j < 4; j++) acc[i][j] = f32x4{0.f, 0.f, 0.f, 0.f};
  for (int j = 0; j < 32; j++) {
    const int kch = j >> 3, kc = j & 7;
    if (kc == 0) {                               // restage A chunk (async, swizzled)
      #pragma unroll
      for (int r = 0; r < 8; r++) {
        int c = r * 256 + t;
        int row = c >> 5, q = (c & 31) ^ (row & 7);
        copy16(G + (size_t)(mb + row) * 1024 + kch * 256 + q * 8,
               Al + (size_t)(r * 256 + w * 64) * 8);
      }
      __syncthreads();                           // A (and, at j=0, B0) landed
    }
    if (j + 1 < 32) {                            // prefetch next B tile (in flight over MFMA)
      const int kch1 = (j + 1) >> 3, kc1 = (j + 1) & 7;
      u16* nxtB = Bl[(j + 1) & 1];
      #pragma unroll
      for (int r = 0; r < 4; r++) {
        int c = r * 256 + t;
        copy16(W2w + (size_t)(c >> 2) * 1024 + kch1 * 256 + kc1 * 32 + (c & 3) * 8,
               nxtB + (size_t)(r * 256 + w * 64) * 8);
      }
    }
    const u16* curB = Bl[j & 1];
    short8 af[4], bfr[4];
    #pragma unroll
    for (int mt = 0; mt < 4; mt++) {
      int row = mt * 16 + lrow;
      af[mt] = *(const short8*)&Al[row * 256 + (((kc * 4 + quad) ^ l7) * 8)];
    }
    #pragma unroll
    for (int nt = 0; nt < 4; nt++)
      bfr[nt] = *(const short8*)&curB[(wn * 64 + nt * 16 + lrow) * 32 + quad * 8];
    #pragma unroll
    for (int mt = 0; mt < 4; mt++)
      #pragma unroll
      for (int nt = 0; nt < 4; nt++)
        acc[mt][nt] = __builtin_amdgcn_mfma_f32_16x16x32_bf16(af[mt], bfr[nt], acc[mt][nt], 0, 0, 0);
    __syncthreads();
  }
  #pragma unroll
  for (int nt = 0; nt < 4; nt++) {
    int n = wn * 64 + nt * 16 + lrow;
    float bv = bias[n];
    #pragma unroll
    for (int mt = 0; mt < 4; mt++)
      #pragma unroll
      for (int i = 0; i < 4; i++) {
        int m = mb + mt * 16 + quad * 4 + i;
        out[((size_t)row0 + m) * 256 + n] = acc[mt][nt][i] + bv + bf2f(xfb[(size_t)m * 256 + n]);
      }
  }
}

// ---------------- host ----------------
#define WEIGHT_BYTES 1572864ull

extern "C" void kernel_launch(void* const* d_in, const int* in_sizes, int n_in,
                              void* d_out, int out_size, void* d_ws, size_t ws_size,
                              hipStream_t stream) {
  const float* x     = (const float*)d_in[0];
  const float* ln1g  = (const float*)d_in[1];
  const float* ln1b  = (const float*)d_in[2];
  const float* qkvw  = (const float*)d_in[3];
  const float* qkvb  = (const float*)d_in[4];
  const float* projw = (const float*)d_in[5];
  const float* projb = (const float*)d_in[6];
  const float* lsc   = (const float*)d_in[7];
  const float* ln2g  = (const float*)d_in[8];
  const float* ln2b  = (const float*)d_in[9];
  const float* w1    = (const float*)d_in[10];
  const float* b1    = (const float*)d_in[11];
  const float* w2    = (const float*)d_in[12];
  const float* b2    = (const float*)d_in[13];
  float* out = (float*)d_out;
  char* wsb = (char*)d_ws;

  u16* wbuf = (u16*)wsb;
  u16* WQ = wbuf;             // [768][256]
  u16* WP = wbuf + 196608;    // [256][256]
  u16* W1 = wbuf + 262144;    // [1024][256]
  u16* W2 = wbuf + 524288;    // [256][1024]

  size_t avail = ws_size > WEIGHT_BYTES ? ws_size - WEIGHT_BYTES : 0;
  int nchunks = 64;
  for (int c = 1; c <= 64; c <<= 1) {
    size_t Rr = 204800u / (unsigned)c;
    if (Rr * 5632ull <= avail) { nchunks = c; break; }
  }
  const int R = 204800 / nchunks;
  char* cb = wsb + WEIGHT_BYTES;
  u16* Ybuf = (u16*)(cb);
  u16* QKVb = (u16*)(cb + (size_t)R * 512);
  u16* Obuf = (u16*)(cb + (size_t)R * 2048);
  u16* XFb  = (u16*)(cb + (size_t)R * 2560);
  u16* Y2b  = (u16*)(cb + (size_t)R * 3072);
  u16* Gbuf = (u16*)(cb + (size_t)R * 3584);

  k0_prep<<<3072, 256, 0, stream>>>(qkvw, projw, w1, w2, wbuf);
  for (int c = 0; c < nchunks; c++) {
    int row0 = c * R;
    k1_ln1<<<R / 4, 256, 0, stream>>>(x, ln1g, ln1b, Ybuf, row0);
    kA_gemm<6, false><<<R / 64, 256, 0, stream>>>(Ybuf, WQ, qkvb, QKVb);
    k3_attn<<<R / 25, 256, 0, stream>>>(QKVb, lsc, Obuf);
    k4_proj<<<R / 64, 256, 0, stream>>>(Obuf, WP, projb, x, ln2g, ln2b, XFb, Y2b, row0);
    kA_gemm<8, true><<<R / 64, 256, 0, stream>>>(Y2b, W1, b1, Gbuf);
    k6_ffn2<<<R / 64, 256, 0, stream>>>(Gbuf, W2, b2, XFb, out, row0);
  }
}

// Round 7
// 1469.542 us; speedup vs baseline: 1.3201x; 1.0669x over previous
//
#include <hip/hip_runtime.h>
#include <stdint.h>

typedef unsigned short u16;
typedef __attribute__((ext_vector_type(8))) short short8;
typedef __attribute__((ext_vector_type(4))) float f32x4;

// ---------------- numeric helpers ----------------
__device__ __forceinline__ float bf2f(u16 v) {
  union { uint32_t u; float f; } x; x.u = ((uint32_t)v) << 16; return x.f;
}
__device__ __forceinline__ u16 f2bf(float f) {
  union { float f; uint32_t u; } x; x.f = f;
  uint32_t u = x.u;
  return (u16)((u + 0x7fffu + ((u >> 16) & 1u)) >> 16);  // RNE
}
__device__ __forceinline__ void unp8(int4 r, float* f) {
  f[0] = __uint_as_float(((uint32_t)r.x) << 16);
  f[1] = __uint_as_float(((uint32_t)r.x) & 0xffff0000u);
  f[2] = __uint_as_float(((uint32_t)r.y) << 16);
  f[3] = __uint_as_float(((uint32_t)r.y) & 0xffff0000u);
  f[4] = __uint_as_float(((uint32_t)r.z) << 16);
  f[5] = __uint_as_float(((uint32_t)r.z) & 0xffff0000u);
  f[6] = __uint_as_float(((uint32_t)r.w) << 16);
  f[7] = __uint_as_float(((uint32_t)r.w) & 0xffff0000u);
}

// tanh-form GELU (harness-verified r6): g = u - u*rcp(exp2(2.3022082*u*(1+0.044715u^2))+1)
#if defined(__has_builtin) && __has_builtin(__builtin_amdgcn_exp2f)
#define EXP2F(x) __builtin_amdgcn_exp2f(x)
#else
#define EXP2F(x) exp2f(x)
#endif
#if defined(__has_builtin) && __has_builtin(__builtin_amdgcn_rcpf)
#define RCPF(x) __builtin_amdgcn_rcpf(x)
#else
#define RCPF(x) (1.0f / (x))
#endif
__device__ __forceinline__ float gelu_f(float u) {
  float e = EXP2F(u * fmaf(0.044715f * u, u, 1.0f) * 2.3022082f);
  return u - u * RCPF(e + 1.0f);
}

// 16B global -> LDS async; lp MUST be wave-uniform (HW adds lane*16)
__device__ __forceinline__ void copy16(const u16* g, u16* l) {
#if defined(__has_builtin) && __has_builtin(__builtin_amdgcn_global_load_lds)
  uintptr_t li = (uintptr_t)l;
  uintptr_t gi = (uintptr_t)g;
  __builtin_amdgcn_global_load_lds((const __attribute__((address_space(1))) uint32_t*)gi,
                                   (__attribute__((address_space(3))) uint32_t*)li, 16, 0, 0);
#else
  *(int4*)l = *(const int4*)g;
#endif
}

// ---------------- K0: weight convert+transpose to bf16 [N][K] ----------------
__global__ __launch_bounds__(256) void k0_prep(const float* __restrict__ qkvw,
                                               const float* __restrict__ projw,
                                               const float* __restrict__ w1,
                                               const float* __restrict__ w2,
                                               u16* __restrict__ wbuf) {
  int idx = blockIdx.x * 256 + threadIdx.x;      // 786432 total
  if (idx < 196608) {                            // qkv_w (256,768) -> [768][256]
    int nn = idx >> 8, kk = idx & 255;
    wbuf[idx] = f2bf(qkvw[kk * 768 + nn]);
  } else if (idx < 262144) {                     // proj_w (256,256) -> [256][256]
    int i = idx - 196608; int nn = i >> 8, kk = i & 255;
    wbuf[idx] = f2bf(projw[kk * 256 + nn]);
  } else if (idx < 524288) {                     // ffn_w1 (256,1024) -> [1024][256]
    int i = idx - 262144; int nn = i >> 8, kk = i & 255;
    wbuf[idx] = f2bf(w1[kk * 1024 + nn]);
  } else {                                       // ffn_w2 (1024,256) -> [256][1024]
    int i = idx - 524288; int nn = i >> 10, kk = i & 1023;
    wbuf[idx] = f2bf(w2[kk * 256 + nn]);
  }
}

// ---------------- K1: LN1, one wave per row ----------------
__global__ __launch_bounds__(256) void k1_ln1(const float* __restrict__ x,
                                              const float* __restrict__ g,
                                              const float* __restrict__ b,
                                              u16* __restrict__ Y, int row0) {
  int t = threadIdx.x; int lr = t >> 6; int lane = t & 63;
  size_t row = (size_t)blockIdx.x * 4 + lr;
  const float4 xv = *(const float4*)&x[((size_t)row0 + row) * 256 + lane * 4];
  float s = xv.x + xv.y + xv.z + xv.w;
  float q = xv.x * xv.x + xv.y * xv.y + xv.z * xv.z + xv.w * xv.w;
  #pragma unroll
  for (int off = 32; off > 0; off >>= 1) { s += __shfl_xor(s, off); q += __shfl_xor(q, off); }
  float mean = s * (1.0f / 256.0f);
  float var  = q * (1.0f / 256.0f) - mean * mean;
  float rstd = rsqrtf(var + 1e-5f);
  const float4 gv = *(const float4*)&g[lane * 4];
  const float4 bv = *(const float4*)&b[lane * 4];
  float y0 = (xv.x - mean) * rstd * gv.x + bv.x;
  float y1 = (xv.y - mean) * rstd * gv.y + bv.y;
  float y2 = (xv.z - mean) * rstd * gv.z + bv.z;
  float y3 = (xv.w - mean) * rstd * gv.w + bv.w;
  uint2 r;
  r.x = (uint32_t)f2bf(y0) | ((uint32_t)f2bf(y1) << 16);
  r.y = (uint32_t)f2bf(y2) | ((uint32_t)f2bf(y3) << 16);
  *(uint2*)&Y[row * 256 + lane * 4] = r;
}

// ---------------- A-stationary GEMM, 2-phase double-buffered B staging ----------------
// C[64 x NB*128] = A[64][256] @ Bw[NB*128][256]^T (+bias, optional GELU), bf16 out.
template <int NB, bool GELU>
__global__ __launch_bounds__(256) void kA_gemm(const u16* __restrict__ A, const u16* __restrict__ Bw,
                                               const float* __restrict__ bias, u16* __restrict__ C) {
  __shared__ u16 Al[64 * 256];        // 32KB, swizzled
  __shared__ u16 Bl[2][128 * 32];     // 2x8KB
  const int t = threadIdx.x, w = t >> 6, lane = t & 63, quad = lane >> 4, lrow = lane & 15, l7 = lane & 7;
  const int wm = w >> 1, wn = w & 1;
  const int mb = blockIdx.x * 64;
  #pragma unroll
  for (int r = 0; r < 8; r++) {                  // stage A (async, swizzled source)
    int c = r * 256 + t;
    int row = c >> 5, q = (c & 31) ^ (row & 7);
    copy16(A + (size_t)(mb + row) * 256 + q * 8, Al + (size_t)(r * 256 + w * 64) * 8);
  }
  #pragma unroll
  for (int r = 0; r < 2; r++) {                  // stage B tile j=0 (nb=0,kc=0)
    int c = r * 256 + t;
    copy16(Bw + (size_t)(c >> 2) * 256 + (c & 3) * 8, Bl[0] + (size_t)(r * 256 + w * 64) * 8);
  }
  __syncthreads();                               // A + B0 ready
  constexpr int JMAX = NB * 8;
  constexpr int LDC = NB * 128;
  f32x4 acc[2][4];
  for (int j = 0; j < JMAX; j++) {
    const int nb = j >> 3, kc = j & 7;
    if (kc == 0) {
      #pragma unroll
      for (int i = 0; i < 2; i++)
        #pragma unroll
        for (int jj = 0; jj < 4; jj++) acc[i][jj] = f32x4{0.f, 0.f, 0.f, 0.f};
    }
    if (j + 1 < JMAX) {                          // prefetch next B tile into other buffer
      const int nb1 = (j + 1) >> 3, kc1 = (j + 1) & 7;
      u16* nxtB = Bl[(j + 1) & 1];
      #pragma unroll
      for (int r = 0; r < 2; r++) {
        int c = r * 256 + t;
        copy16(Bw + (size_t)(nb1 * 128 + (c >> 2)) * 256 + kc1 * 32 + (c & 3) * 8,
               nxtB + (size_t)(r * 256 + w * 64) * 8);
      }
    }
    const u16* curB = Bl[j & 1];
    short8 af[2], bfr[4];
    #pragma unroll
    for (int mt = 0; mt < 2; mt++) {
      int row = wm * 32 + mt * 16 + lrow;
      af[mt] = *(const short8*)&Al[row * 256 + (((kc * 4 + quad) ^ l7) * 8)];
    }
    #pragma unroll
    for (int nt = 0; nt < 4; nt++)
      bfr[nt] = *(const short8*)&curB[(wn * 64 + nt * 16 + lrow) * 32 + quad * 8];
    #pragma unroll
    for (int mt = 0; mt < 2; mt++)
      #pragma unroll
      for (int nt = 0; nt < 4; nt++)
        acc[mt][nt] = __builtin_amdgcn_mfma_f32_16x16x32_bf16(af[mt], bfr[nt], acc[mt][nt], 0, 0, 0);
    __syncthreads();                             // prefetch landed; all waves synced
    if (kc == 7) {
      #pragma unroll
      for (int nt = 0; nt < 4; nt++) {
        int n = nb * 128 + wn * 64 + nt * 16 + lrow;
        float bv = bias[n];
        #pragma unroll
        for (int mt = 0; mt < 2; mt++)
          #pragma unroll
          for (int i = 0; i < 4; i++) {
            int m = mb + wm * 32 + mt * 16 + quad * 4 + i;
            float u = acc[mt][nt][i] + bv;
            if (GELU) u = gelu_f(u);
            C[(size_t)m * LDC + n] = f2bf(u);
          }
      }
    }
  }
}

// ---------------- K3: cosine attention via MFMA (unchanged, harness-verified) ----------------
__global__ __launch_bounds__(256) void k3_attn(const u16* __restrict__ QKV,
                                               const float* __restrict__ lscale,
                                               u16* __restrict__ O) {
  __shared__ u16 Kl[8192];         // [vr][256] chunk-XOR swizzled; rows 25..31 uninit (masked)
  __shared__ u16 Vt[10304];        // [h](stride 1288)[d](stride 40)[kr]; kr 25..31 zeroed
  __shared__ u16 Pl[4][1280];      // per-wave P: [q](stride 40)[kr]
  __shared__ float invk[256];      // [h][kr] 1/max(||k||,eps); kr 25..31 zeroed

  const int n = blockIdx.x;
  const int t = threadIdx.x;
  const int w = t >> 6, lane = t & 63, quad = lane >> 4, l15 = lane & 15;
  const size_t n25 = (size_t)n * 25;

  #pragma unroll
  for (int r = 0; r < 4; r++) {
    int c = r * 256 + t;
    if (c < 800) {
      int vr = c >> 5, ci = c & 31;
      const u16* gp = QKV + (n25 + vr) * 768 + 256 + (size_t)((ci ^ (vr & 7)) * 8);
      u16* lp = Kl + (size_t)(r * 256 + w * 64) * 8;          // wave-uniform base
      copy16(gp, lp);
    }
  }
  #pragma unroll
  for (int r = 0; r < 4; r++) {
    int c = r * 256 + t;
    if (c < 800) {
      int vr = c >> 5, ci = c & 31, h = ci >> 2, d8 = (ci & 3) * 8;
      int4 rv = *(const int4*)&QKV[(n25 + vr) * 768 + 512 + ci * 8];
      int base = h * 1288 + d8 * 40 + vr;
      Vt[base +   0] = (u16)((uint32_t)rv.x & 0xffffu);
      Vt[base +  40] = (u16)((uint32_t)rv.x >> 16);
      Vt[base +  80] = (u16)((uint32_t)rv.y & 0xffffu);
      Vt[base + 120] = (u16)((uint32_t)rv.y >> 16);
      Vt[base + 160] = (u16)((uint32_t)rv.z & 0xffffu);
      Vt[base + 200] = (u16)((uint32_t)rv.z >> 16);
      Vt[base + 240] = (u16)((uint32_t)rv.w & 0xffffu);
      Vt[base + 280] = (u16)((uint32_t)rv.w >> 16);
    }
  }
  {
    int h = t >> 5, d = t & 31;
    int base = h * 1288 + d * 40 + 25;
    #pragma unroll
    for (int j = 0; j < 7; j++) Vt[base + j] = 0;
  }
  __syncthreads();

  if (t < 200) {
    int h = (t * 41) >> 10;                      // t/25 for t<200
    int vr = t - h * 25;
    float ss = 0.f;
    #pragma unroll
    for (int q = 0; q < 4; q++) {
      int chunk = (h * 4 + q) ^ (vr & 7);
      int4 rv = *(const int4*)&Kl[vr * 256 + chunk * 8];
      float f[8]; unp8(rv, f);
      #pragma unroll
      for (int j = 0; j < 8; j++) ss += f[j] * f[j];
    }
    invk[h * 32 + vr] = 1.0f / fmaxf(sqrtf(ss), 1e-12f);
  } else {
    int u = t - 200;
    int h = (u * 37) >> 8;                       // u/7 for u<56
    int j = u - h * 7;
    invk[h * 32 + 25 + j] = 0.f;
  }
  __syncthreads();

  const u16* qbase = QKV + n25 * 768;
  const f32x4 zz = {0.f, 0.f, 0.f, 0.f};
  #pragma unroll
  for (int hh = 0; hh < 2; hh++) {
    const int h = w * 2 + hh;
    const float sc = expf(fminf(lscale[h], 4.6051701859880913680f));   // min(ls, ln 100)

    short8 af0 = *(const short8*)(qbase + (size_t)l15 * 768 + h * 32 + quad * 8);
    short8 af1 = *(const short8*)(qbase + (size_t)(16 + l15) * 768 + h * 32 + quad * 8);
    short8 bf0 = *(const short8*)&Kl[l15 * 256 + (((h * 4 + quad) ^ (l15 & 7)) * 8)];
    short8 bf1 = *(const short8*)&Kl[(16 + l15) * 256 + (((h * 4 + quad) ^ ((16 + l15) & 7)) * 8)];
    f32x4 sA[2][2];
    sA[0][0] = __builtin_amdgcn_mfma_f32_16x16x32_bf16(af0, bf0, zz, 0, 0, 0);
    sA[0][1] = __builtin_amdgcn_mfma_f32_16x16x32_bf16(af0, bf1, zz, 0, 0, 0);
    sA[1][0] = __builtin_amdgcn_mfma_f32_16x16x32_bf16(af1, bf0, zz, 0, 0, 0);
    sA[1][1] = __builtin_amdgcn_mfma_f32_16x16x32_bf16(af1, bf1, zz, 0, 0, 0);

    float ss0 = 0.f, ss1 = 0.f;
    #pragma unroll
    for (int j = 0; j < 8; j++) {
      float f0 = bf2f((u16)af0[j]); ss0 += f0 * f0;
      float f1 = bf2f((u16)af1[j]); ss1 += f1 * f1;
    }
    ss0 += __shfl_xor(ss0, 16); ss0 += __shfl_xor(ss0, 32);
    ss1 += __shfl_xor(ss1, 16); ss1 += __shfl_xor(ss1, 32);
    float fct0 = sc / (fmaxf(sqrtf(ss0), 1e-12f) * 5.6568542494923802f);
    float fct1 = sc / (fmaxf(sqrtf(ss1), 1e-12f) * 5.6568542494923802f);

    const float ik0 = invk[h * 32 + l15];
    const float ik1 = invk[h * 32 + 16 + l15];
    const bool v1 = l15 < 9;

    #pragma unroll
    for (int qt = 0; qt < 2; qt++) {
      #pragma unroll
      for (int i = 0; i < 4; i++) {
        float fr = __shfl(qt == 0 ? fct0 : fct1, quad * 4 + i);
        float l0 = sA[qt][0][i] * fr * ik0;
        float l1 = sA[qt][1][i] * fr * ik1;
        float m = fmaxf(l0, v1 ? l1 : -1e30f);
        #pragma unroll
        for (int o = 1; o < 16; o <<= 1) m = fmaxf(m, __shfl_xor(m, o));
        float e0 = expf(l0 - m);
        float e1 = v1 ? expf(l1 - m) : 0.f;
        float se = e0 + e1;
        #pragma unroll
        for (int o = 1; o < 16; o <<= 1) se += __shfl_xor(se, o);
        float inv = 1.0f / se;
        int q = qt * 16 + quad * 4 + i;
        Pl[w][q * 40 + l15]      = f2bf(e0 * inv);
        Pl[w][q * 40 + 16 + l15] = f2bf(e1 * inv);
      }
    }

    short8 pa0 = *(const short8*)&Pl[w][l15 * 40 + quad * 8];
    short8 pa1 = *(const short8*)&Pl[w][(16 + l15) * 40 + quad * 8];
    short8 vb0 = *(const short8*)&Vt[h * 1288 + l15 * 40 + quad * 8];
    short8 vb1 = *(const short8*)&Vt[h * 1288 + (16 + l15) * 40 + quad * 8];
    f32x4 oA[2][2];
    oA[0][0] = __builtin_amdgcn_mfma_f32_16x16x32_bf16(pa0, vb0, zz, 0, 0, 0);
    oA[0][1] = __builtin_amdgcn_mfma_f32_16x16x32_bf16(pa0, vb1, zz, 0, 0, 0);
    oA[1][0] = __builtin_amdgcn_mfma_f32_16x16x32_bf16(pa1, vb0, zz, 0, 0, 0);
    oA[1][1] = __builtin_amdgcn_mfma_f32_16x16x32_bf16(pa1, vb1, zz, 0, 0, 0);

    u16* ob = O + n25 * 256 + h * 32;
    #pragma unroll
    for (int qt = 0; qt < 2; qt++)
      #pragma unroll
      for (int i = 0; i < 4; i++) {
        int qr = quad * 4 + i;
        if (qt == 1 && qr >= 9) continue;
        int q = qt * 16 + qr;
        ob[(size_t)q * 256 + l15]      = f2bf(oA[qt][0][i]);
        ob[(size_t)q * 256 + 16 + l15] = f2bf(oA[qt][1][i]);
      }
  }
}

// ---------------- K4: xf = O@Wp + b + x; fused LN2 -> xf(bf16), y2(bf16) ----------------
__global__ __launch_bounds__(256) void k4_proj(const u16* __restrict__ A, const u16* __restrict__ Bw,
                                               const float* __restrict__ bias,
                                               const float* __restrict__ x,
                                               const float* __restrict__ g2, const float* __restrict__ b2,
                                               u16* __restrict__ xfb, u16* __restrict__ y2b, int row0) {
  __shared__ u16 Al[64 * 256];        // 32KB swizzled
  __shared__ u16 Bl[2][256 * 32];     // 2x16KB
  __shared__ float ps[4][64], pq[4][64], meanv[64], rstdv[64];
  const int t = threadIdx.x, w = t >> 6, lane = t & 63, quad = lane >> 4, lrow = lane & 15, l7 = lane & 7;
  const int wn = w;
  const int mb = blockIdx.x * 64;
  #pragma unroll
  for (int r = 0; r < 8; r++) {                  // stage A (async, swizzled)
    int c = r * 256 + t;
    int row = c >> 5, q = (c & 31) ^ (row & 7);
    copy16(A + (size_t)(mb + row) * 256 + q * 8, Al + (size_t)(r * 256 + w * 64) * 8);
  }
  #pragma unroll
  for (int r = 0; r < 4; r++) {                  // stage B tile kc=0
    int c = r * 256 + t;
    copy16(Bw + (size_t)(c >> 2) * 256 + (c & 3) * 8, Bl[0] + (size_t)(r * 256 + w * 64) * 8);
  }
  __syncthreads();
  f32x4 acc[4][4];
  #pragma unroll
  for (int i = 0; i < 4; i++)
    #pragma unroll
    for (int j = 0; j < 4; j++) acc[i][j] = f32x4{0.f, 0.f, 0.f, 0.f};
  for (int j = 0; j < 8; j++) {
    if (j + 1 < 8) {                             // prefetch next B tile
      u16* nxtB = Bl[(j + 1) & 1];
      #pragma unroll
      for (int r = 0; r < 4; r++) {
        int c = r * 256 + t;
        copy16(Bw + (size_t)(c >> 2) * 256 + (j + 1) * 32 + (c & 3) * 8,
               nxtB + (size_t)(r * 256 + w * 64) * 8);
      }
    }
    const u16* curB = Bl[j & 1];
    short8 af[4], bfr[4];
    #pragma unroll
    for (int mt = 0; mt < 4; mt++) {
      int row = mt * 16 + lrow;
      af[mt] = *(const short8*)&Al[row * 256 + (((j * 4 + quad) ^ l7) * 8)];
    }
    #pragma unroll
    for (int nt = 0; nt < 4; nt++)
      bfr[nt] = *(const short8*)&curB[(wn * 64 + nt * 16 + lrow) * 32 + quad * 8];
    #pragma unroll
    for (int mt = 0; mt < 4; mt++)
      #pragma unroll
      for (int nt = 0; nt < 4; nt++)
        acc[mt][nt] = __builtin_amdgcn_mfma_f32_16x16x32_bf16(af[mt], bfr[nt], acc[mt][nt], 0, 0, 0);
    __syncthreads();
  }
  #pragma unroll
  for (int nt = 0; nt < 4; nt++) {
    int nn = wn * 64 + nt * 16 + lrow;
    float bv = bias[nn];
    #pragma unroll
    for (int mt = 0; mt < 4; mt++)
      #pragma unroll
      for (int i = 0; i < 4; i++) {
        int m = mb + mt * 16 + quad * 4 + i;
        acc[mt][nt][i] += bv + x[((size_t)row0 + m) * 256 + nn];
      }
  }
  #pragma unroll
  for (int mt = 0; mt < 4; mt++)
    #pragma unroll
    for (int i = 0; i < 4; i++) {
      float s = 0.f, q = 0.f;
      #pragma unroll
      for (int nt = 0; nt < 4; nt++) { float v = acc[mt][nt][i]; s += v; q += v * v; }
      #pragma unroll
      for (int off = 1; off < 16; off <<= 1) { s += __shfl_xor(s, off); q += __shfl_xor(q, off); }
      if (lrow == 0) { int r = mt * 16 + quad * 4 + i; ps[w][r] = s; pq[w][r] = q; }
    }
  __syncthreads();
  if (t < 64) {
    float s = ps[0][t] + ps[1][t] + ps[2][t] + ps[3][t];
    float q = pq[0][t] + pq[1][t] + pq[2][t] + pq[3][t];
    float mean = s * (1.0f / 256.0f);
    float var  = q * (1.0f / 256.0f) - mean * mean;
    meanv[t] = mean; rstdv[t] = rsqrtf(var + 1e-5f);
  }
  __syncthreads();
  #pragma unroll
  for (int nt = 0; nt < 4; nt++) {
    int nn = wn * 64 + nt * 16 + lrow;
    float gg = g2[nn], bb = b2[nn];
    #pragma unroll
    for (int mt = 0; mt < 4; mt++)
      #pragma unroll
      for (int i = 0; i < 4; i++) {
        int r = mt * 16 + quad * 4 + i;
        int m = mb + r;
        float xfv = acc[mt][nt][i];
        xfb[(size_t)m * 256 + nn] = f2bf(xfv);
        y2b[(size_t)m * 256 + nn] = f2bf((xfv - meanv[r]) * rstdv[r] * gg + bb);
      }
  }
}

// ---------------- K6: out = xf + G @ W2 + b2; BM=128, dual-sliced dbuf, 2-phase ----------------
// 4 waves in 2x2; wave tile 64x128; acc[4][8]. Per K-step(32): stage A-slice 128x32
// (2 ld/thr) + B-slice 256x32 (4 ld/thr) into the other buffer, 32 MFMA/wave, one barrier.
// 2x compute per barrier vs BM=64 and no serial A-restage; LDS 48KB.
__global__ __launch_bounds__(256, 2) void k6_ffn2(const u16* __restrict__ G, const u16* __restrict__ W2w,
                                                  const float* __restrict__ bias,
                                                  const u16* __restrict__ xfb,
                                                  float* __restrict__ out, int row0) {
  __shared__ u16 Asl[2][128 * 32];    // 2x8KB
  __shared__ u16 Bsl[2][256 * 32];    // 2x16KB
  const int t = threadIdx.x, w = t >> 6, lane = t & 63, quad = lane >> 4, lrow = lane & 15;
  const int wm = w >> 1, wn = w & 1;
  const int mb = blockIdx.x * 128;
  auto stage = [&](int s, int buf) {
    #pragma unroll
    for (int r = 0; r < 2; r++) {               // A-slice 128 rows x 32 k
      int c = r * 256 + t;
      copy16(G + (size_t)(mb + (c >> 2)) * 1024 + s * 32 + (c & 3) * 8,
             Asl[buf] + (size_t)(r * 256 + w * 64) * 8);
    }
    #pragma unroll
    for (int r = 0; r < 4; r++) {               // B-slice 256 rows x 32 k
      int c = r * 256 + t;
      copy16(W2w + (size_t)(c >> 2) * 1024 + s * 32 + (c & 3) * 8,
             Bsl[buf] + (size_t)(r * 256 + w * 64) * 8);
    }
  };
  stage(0, 0);
  __syncthreads();
  f32x4 acc[4][8];
  #pragma unroll
  for (int i = 0; i < 4; i++)
    #pragma unroll
    for (int j = 0; j < 8; j++) acc[i][j] = f32x4{0.f, 0.f, 0.f, 0.f};
  for (int s = 0; s < 32; s++) {
    const int buf = s & 1;
    if (s + 1 < 32) stage(s + 1, buf ^ 1);       // prefetch flies over this step's MFMAs
    short8 af[4], bfr[8];
    #pragma unroll
    for (int mt = 0; mt < 4; mt++)
      af[mt] = *(const short8*)&Asl[buf][(wm * 64 + mt * 16 + lrow) * 32 + quad * 8];
    #pragma unroll
    for (int nt = 0; nt < 8; nt++)
      bfr[nt] = *(const short8*)&Bsl[buf][(wn * 128 + nt * 16 + lrow) * 32 + quad * 8];
    #pragma unroll
    for (int mt = 0; mt < 4; mt++)
      #pragma unroll
      for (int nt = 0; nt < 8; nt++)
        acc[mt][nt] = __builtin_amdgcn_mfma_f32_16x16x32_bf16(af[mt], bfr[nt], acc[mt][nt], 0, 0, 0);
    __syncthreads();
  }
  #pragma unroll
  for (int nt = 0; nt < 8; nt++) {
    int n = wn * 128 + nt * 16 + lrow;
    float bv = bias[n];
    #pragma unroll
    for (int mt = 0; mt < 4; mt++)
      #pragma unroll
      for (int i = 0; i < 4; i++) {
        int m = mb + wm * 64 + mt * 16 + quad * 4 + i;
        out[((size_t)row0 + m) * 256 + n] = acc[mt][nt][i] + bv + bf2f(xfb[(size_t)m * 256 + n]);
      }
  }
}

// ---------------- host ----------------
#define WEIGHT_BYTES 1572864ull

extern "C" void kernel_launch(void* const* d_in, const int* in_sizes, int n_in,
                              void* d_out, int out_size, void* d_ws, size_t ws_size,
                              hipStream_t stream) {
  const float* x     = (const float*)d_in[0];
  const float* ln1g  = (const float*)d_in[1];
  const float* ln1b  = (const float*)d_in[2];
  const float* qkvw  = (const float*)d_in[3];
  const float* qkvb  = (const float*)d_in[4];
  const float* projw = (const float*)d_in[5];
  const float* projb = (const float*)d_in[6];
  const float* lsc   = (const float*)d_in[7];
  const float* ln2g  = (const float*)d_in[8];
  const float* ln2b  = (const float*)d_in[9];
  const float* w1    = (const float*)d_in[10];
  const float* b1    = (const float*)d_in[11];
  const float* w2    = (const float*)d_in[12];
  const float* b2    = (const float*)d_in[13];
  float* out = (float*)d_out;
  char* wsb = (char*)d_ws;

  u16* wbuf = (u16*)wsb;
  u16* WQ = wbuf;             // [768][256]
  u16* WP = wbuf + 196608;    // [256][256]
  u16* W1 = wbuf + 262144;    // [1024][256]
  u16* W2 = wbuf + 524288;    // [256][1024]

  size_t avail = ws_size > WEIGHT_BYTES ? ws_size - WEIGHT_BYTES : 0;
  int nchunks = 64;
  for (int c = 1; c <= 64; c <<= 1) {
    size_t Rr = 204800u / (unsigned)c;
    if (Rr * 5632ull <= avail) { nchunks = c; break; }
  }
  const int R = 204800 / nchunks;
  char* cb = wsb + WEIGHT_BYTES;
  u16* Ybuf = (u16*)(cb);
  u16* QKVb = (u16*)(cb + (size_t)R * 512);
  u16* Obuf = (u16*)(cb + (size_t)R * 2048);
  u16* XFb  = (u16*)(cb + (size_t)R * 2560);
  u16* Y2b  = (u16*)(cb + (size_t)R * 3072);
  u16* Gbuf = (u16*)(cb + (size_t)R * 3584);

  k0_prep<<<3072, 256, 0, stream>>>(qkvw, projw, w1, w2, wbuf);
  for (int c = 0; c < nchunks; c++) {
    int row0 = c * R;
    k1_ln1<<<R / 4, 256, 0, stream>>>(x, ln1g, ln1b, Ybuf, row0);
    kA_gemm<6, false><<<R / 64, 256, 0, stream>>>(Ybuf, WQ, qkvb, QKVb);
    k3_attn<<<R / 25, 256, 0, stream>>>(QKVb, lsc, Obuf);
    k4_proj<<<R / 64, 256, 0, stream>>>(Obuf, WP, projb, x, ln2g, ln2b, XFb, Y2b, row0);
    kA_gemm<8, true><<<R / 64, 256, 0, stream>>>(Y2b, W1, b1, Gbuf);
    k6_ffn2<<<R / 128, 256, 0, stream>>>(Gbuf, W2, b2, XFb, out, row0);
  }
}